// Round 4
// baseline (321.140 us; speedup 1.0000x reference)
//
#include <hip/hip_runtime.h>
#include <math.h>

#define HWSZ 4096   // 64*64
#define LDP 68      // padded LDS tile stride
#define QSCALE 0.17677669529663687f  // 1/sqrt(32)

typedef __bf16 bf16x2 __attribute__((ext_vector_type(2)));
typedef __bf16 bf16x4 __attribute__((ext_vector_type(4)));
typedef __bf16 bf16x8 __attribute__((ext_vector_type(8)));
typedef float  f32x4  __attribute__((ext_vector_type(4)));

// ---------------- scrambled-token LayerNorm -> qnb [8192][256] bf16 ----------------
__global__ __launch_bounds__(256) void ln_qn_kernel(
    const float* __restrict__ F, const float* __restrict__ lnw,
    const float* __restrict__ lnb, __bf16* __restrict__ qnb)
{
  __shared__ float sm[256][20];
  int bw = blockIdx.x;                 // b*256 + w
  int b = bw >> 8, w = bw & 255;
  int wy = w >> 4, wx = w & 15;
  int tid = threadIdx.x;               // = channel c
  const float* Fb = F + ((size_t)(b*256 + tid))*HWSZ + (wy*4)*64 + wx*4;
  #pragma unroll
  for (int py = 0; py < 4; ++py) {
    float4 v = *(const float4*)(Fb + py*64);
    sm[tid][py*4+0] = v.x; sm[tid][py*4+1] = v.y;
    sm[tid][py*4+2] = v.z; sm[tid][py*4+3] = v.w;
  }
  __syncthreads();
  int t = tid >> 4, th = tid & 15;
  float vals[16], s1 = 0.f, s2 = 0.f;
  #pragma unroll
  for (int p = 0; p < 16; ++p) {
    float x = sm[t*16 + th][p];
    vals[p] = x; s1 += x; s2 += x*x;
  }
  #pragma unroll
  for (int m = 1; m < 16; m <<= 1) { s1 += __shfl_xor(s1, m); s2 += __shfl_xor(s2, m); }
  float mean = s1 * (1.f/256.f);
  float var  = s2 * (1.f/256.f) - mean*mean;
  float rstd = rsqrtf(var + 1e-5f);
  __bf16* outp = qnb + ((size_t)(bw*16 + t))*256 + th*16;
  bf16x8 o0, o1;
  #pragma unroll
  for (int p = 0; p < 8; ++p) {
    o0[p] = (__bf16)((vals[p]-mean)*rstd*lnw[th*16+p] + lnb[th*16+p]);
    o1[p] = (__bf16)((vals[p+8]-mean)*rstd*lnw[th*16+p+8] + lnb[th*16+p+8]);
  }
  *(bf16x8*)outp = o0;
  *(bf16x8*)(outp+8) = o1;
}

// ---------------- pools (channel-major) ----------------
__global__ __launch_bounds__(256) void pool_mid_kernel(const float* __restrict__ F, float* __restrict__ mid)
{
  int idx = blockIdx.x*256 + threadIdx.x;
  int bc = idx >> 10, yx = idx & 1023;
  int my = yx >> 5, mx = yx & 31;
  const float* p = F + (size_t)bc*HWSZ + (my*2)*64 + mx*2;
  mid[idx] = 0.25f*(p[0] + p[1] + p[64] + p[65]);
}
__global__ __launch_bounds__(256) void pool_glb_kernel(const float* __restrict__ mid, float* __restrict__ glb)
{
  int idx = blockIdx.x*256 + threadIdx.x;
  int bc = idx >> 8, yx = idx & 255;
  int gy = yx >> 4, gx = yx & 15;
  const float* p = mid + (size_t)bc*1024 + (gy*2)*32 + gx*2;
  glb[idx] = 0.25f*(p[0] + p[1] + p[32] + p[33]);
}

// ---------------- one-time: WT[n][k] = bf16(W[k][n]), K fixed 256 ----------------
__global__ __launch_bounds__(256) void transpose_w(
    const float* __restrict__ W, __bf16* __restrict__ WT, int ncols)
{
  __shared__ float T[64][68];
  int n0 = blockIdx.x*64, k0 = blockIdx.y*64;
  int tid = threadIdx.x;
  int c4 = (tid & 15)*4, rr = tid >> 4;
  #pragma unroll
  for (int p = 0; p < 4; ++p) {
    int row = p*16 + rr;
    float4 v = *(const float4*)(W + (size_t)(k0+row)*ncols + n0 + c4);
    T[c4+0][row] = v.x; T[c4+1][row] = v.y; T[c4+2][row] = v.z; T[c4+3][row] = v.w;
  }
  __syncthreads();
  #pragma unroll
  for (int p = 0; p < 4; ++p) {
    int cc = p*16 + rr;
    bf16x4 o;
    o[0] = (__bf16)T[cc][c4+0]; o[1] = (__bf16)T[cc][c4+1];
    o[2] = (__bf16)T[cc][c4+2]; o[3] = (__bf16)T[cc][c4+3];
    *(bf16x4*)(WT + (size_t)(n0+cc)*256 + k0 + c4) = o;
  }
}

// ---------------- q GEMM (MFMA, swapped operands): qbf = bf16((qnb@W[:, :256]+b)*QSCALE)
// wave = (window, n-half). D[m=ch quad*4+r][n=token col] -> bf16x4 stores.
__global__ __launch_bounds__(256) void gemm_q_mfma(
    const __bf16* __restrict__ qnb, const __bf16* __restrict__ WT,
    const float* __restrict__ qkvb, __bf16* __restrict__ qbf)
{
  int tid = threadIdx.x, wv = tid >> 6, lane = tid & 63;
  int col = lane & 15, quad = lane >> 4;
  int win = blockIdx.x*2 + (wv >> 1);
  int nbase = (wv & 1)*8;
  bf16x8 bq[8];
  const __bf16* qp = qnb + ((size_t)win*16 + col)*256 + quad*8;
  #pragma unroll
  for (int kk = 0; kk < 8; ++kk) bq[kk] = *(const bf16x8*)(qp + kk*32);
  const f32x4 zero = {0.f,0.f,0.f,0.f};
  #pragma unroll
  for (int nt = 0; nt < 8; ++nt) {
    int n0 = (nbase+nt)*16;
    const __bf16* wp = WT + ((size_t)(n0+col))*256 + quad*8;
    f32x4 acc = zero;
    #pragma unroll
    for (int kk = 0; kk < 8; ++kk) {
      bf16x8 wf = *(const bf16x8*)(wp + kk*32);
      acc = __builtin_amdgcn_mfma_f32_16x16x32_bf16(wf, bq[kk], acc, 0, 0, 0);
    }
    float4 b4 = *(const float4*)(qkvb + n0 + quad*4);
    float bb[4] = {b4.x,b4.y,b4.z,b4.w};
    bf16x4 o;
    #pragma unroll
    for (int r = 0; r < 4; ++r) o[r] = (__bf16)((acc[r]+bb[r])*QSCALE);
    *(bf16x4*)(qbf + ((size_t)win*16 + col)*256 + n0 + quad*4) = o;
  }
}

// ---------------- local KV: MFMA, one block per window, A gathered ONCE ----------------
__global__ __launch_bounds__(256) void loc_kv_mfma(
    const float* __restrict__ F, const __bf16* __restrict__ WT,
    const float* __restrict__ qkvb,
    __bf16* __restrict__ kloc, __bf16* __restrict__ vloct)
{
  __shared__ __bf16 As[64*264];
  int bw = blockIdx.x;
  int b = bw >> 8, w = bw & 255;
  int wy4 = ((w >> 4) << 2) - 2, wx4 = ((w & 15) << 2) - 2;
  int tid = threadIdx.x;
  {
    int xp = tid & 3;
    int dy = (tid >> 2) & 7;
    int cg = tid >> 5;
    int yy = wy4 + dy, xx = wx4 + xp*2;
    bool inb = ((unsigned)yy < 64u) && ((unsigned)xx < 64u);
    const float* Fp = F + ((size_t)b*256)*HWSZ + yy*64 + xx;
    #pragma unroll 4
    for (int i = 0; i < 32; ++i) {
      int ch = cg*32 + i;
      float2 v = make_float2(0.f, 0.f);
      if (inb) v = *(const float2*)(Fp + (size_t)ch*HWSZ);
      int t = ch >> 2, r = ch & 3;
      bf16x2 o; o[0] = (__bf16)v.x; o[1] = (__bf16)v.y;
      *(bf16x2*)&As[t*264 + r*64 + dy*8 + xp*2] = o;
    }
  }
  __syncthreads();
  int wv = tid >> 6, lane = tid & 63;
  int col = lane & 15, quad = lane >> 4;
  int m0 = wv*16;
  bf16x8 af[8];
  #pragma unroll
  for (int kk = 0; kk < 8; ++kk)
    af[kk] = *(const bf16x8*)&As[(m0+col)*264 + kk*32 + quad*8];

  const f32x4 zero = {0.f,0.f,0.f,0.f};
  #pragma unroll 2
  for (int nt = 0; nt < 32; ++nt) {
    int n = nt*16 + col;
    float bias_n = qkvb[256 + n];
    const __bf16* Wp = WT + (size_t)(256 + n)*256 + quad*8;
    f32x4 acc = zero;
    #pragma unroll
    for (int kk = 0; kk < 8; ++kk) {
      bf16x8 bv = *(const bf16x8*)(Wp + kk*32);
      acc = __builtin_amdgcn_mfma_f32_16x16x32_bf16(af[kk], bv, acc, 0, 0, 0);
    }
    if (nt < 16) {
      #pragma unroll
      for (int r = 0; r < 4; ++r)
        kloc[((size_t)bw*64 + m0 + quad*4 + r)*256 + n] = (__bf16)(acc[r] + bias_n);
    } else {
      bf16x4 o;
      #pragma unroll
      for (int r = 0; r < 4; ++r) o[r] = (__bf16)(acc[r] + bias_n);
      *(bf16x4*)(vloct + ((size_t)bw*256 + (n - 256))*64 + m0 + quad*4) = o;
    }
  }
}

// ---------------- mid/glb KV GEMM: A col-major [256][M], batched ----------------
__global__ __launch_bounds__(256) void gemm_mg_kv(
    const float* __restrict__ A, int Mstride, int Abatch,
    const float* __restrict__ Bw, const float* __restrict__ qkvb,
    __bf16* __restrict__ kdst, size_t kbatch,
    __bf16* __restrict__ vdst, size_t vbatch, int vstride)
{
  __shared__ float As[16][LDP];
  __shared__ float Bs[16][LDP];
  int bz = blockIdx.z;
  A += (size_t)bz*Abatch; kdst += (size_t)bz*kbatch; vdst += (size_t)bz*vbatch;
  int m0 = blockIdx.x*64;
  int nc = blockIdx.y;
  int bcol = 256 + nc*64;
  int tid = threadIdx.x, tx = tid & 15, ty = tid >> 4;
  float acc[4][4] = {};
  for (int k0 = 0; k0 < 256; k0 += 16) {
    {
      int kk = tid >> 4, mm = (tid & 15)*4;
      *(float4*)&As[kk][mm] = *(const float4*)(A + (size_t)(k0+kk)*Mstride + m0 + mm);
    }
    {
      int kk = tid >> 4, nn = (tid & 15)*4;
      *(float4*)&Bs[kk][nn] = *(const float4*)(Bw + (size_t)(k0+kk)*768 + bcol + nn);
    }
    __syncthreads();
    #pragma unroll
    for (int k = 0; k < 16; ++k) {
      float4 a = *(const float4*)&As[k][ty*4];
      float4 bv = *(const float4*)&Bs[k][tx*4];
      float av[4] = {a.x,a.y,a.z,a.w};
      float bb[4] = {bv.x,bv.y,bv.z,bv.w};
      #pragma unroll
      for (int i = 0; i < 4; ++i)
        #pragma unroll
        for (int j = 0; j < 4; ++j) acc[i][j] += av[i]*bb[j];
    }
    __syncthreads();
  }
  float4 b4 = *(const float4*)(qkvb + bcol + tx*4);
  float bb[4] = {b4.x,b4.y,b4.z,b4.w};
  if (nc < 4) {
    int n0 = nc*64;
    #pragma unroll
    for (int i = 0; i < 4; ++i) {
      bf16x4 o;
      #pragma unroll
      for (int j = 0; j < 4; ++j) o[j] = (__bf16)(acc[i][j]+bb[j]);
      *(bf16x4*)(kdst + (size_t)(m0+ty*4+i)*256 + n0 + tx*4) = o;
    }
  } else {
    int d0 = (nc-4)*64;
    #pragma unroll
    for (int j = 0; j < 4; ++j) {
      bf16x4 o;
      #pragma unroll
      for (int i = 0; i < 4; ++i) o[i] = (__bf16)(acc[i][j]+bb[j]);
      *(bf16x4*)(vdst + (size_t)(d0+tx*4+j)*vstride + m0 + ty*4) = o;
    }
  }
}

// ---------------- MFMA fused attention, split-K: block = window, 16 waves ----------------
// wave = (head, key-half): half 0 -> chunks 0..20 (incl. local), half 1 -> 21..41.
// Plain sum-exp (scores bounded) => halves merge by simple add of (O, l) in LDS.
__global__ __launch_bounds__(1024, 8) void attn_mfma(
    const __bf16* __restrict__ qbf, const __bf16* __restrict__ kloc,
    const __bf16* __restrict__ vloct, const __bf16* __restrict__ kmg,
    const __bf16* __restrict__ vmgt, __bf16* __restrict__ obf)
{
  __shared__ __bf16 Pb[16][2][16][40];   // 40960 B, per-wave double buffer
  __shared__ float  Mg[8][64][12];       // 24576 B, half-1 partials
  int bw = blockIdx.x, b = bw >> 8;
  int tid = threadIdx.x;
  int wv = tid >> 6, lane = tid & 63;
  int h = wv & 7, half = wv >> 3;
  int col = lane & 15, quad = lane >> 4;

  bf16x8 aq = *(const bf16x8*)(qbf + ((size_t)(bw*16 + col))*256 + h*32 + quad*8);
  f32x4 O0 = {0.f,0.f,0.f,0.f}, O1 = {0.f,0.f,0.f,0.f};
  const f32x4 zero = {0.f,0.f,0.f,0.f};
  float ls[4] = {0.f,0.f,0.f,0.f};

  const __bf16* klocb = kloc + (size_t)bw*16384;
  const __bf16* vlocb = vloct + (size_t)bw*16384;
  const __bf16* kmgb  = kmg + (size_t)b*327680;
  const __bf16* vmgb  = vmgt + (size_t)b*327680;

  int chBeg = half*21, chEnd = chBeg + 21;
  bf16x8 nk0, nk1;
  {
    const __bf16* kb = (chBeg < 2) ? klocb + (size_t)(chBeg*32)*256
                                   : kmgb + (size_t)((chBeg-2)*32)*256;
    nk0 = *(const bf16x8*)(kb + (size_t)col*256 + h*32 + quad*8);
    nk1 = *(const bf16x8*)(kb + (size_t)(16+col)*256 + h*32 + quad*8);
  }
  for (int ch = chBeg; ch < chEnd; ++ch) {
    bf16x8 k0 = nk0, k1 = nk1;
    const __bf16* vb; int tok0, vstr;
    if (ch < 2) { vb = vlocb; tok0 = ch*32;     vstr = 64; }
    else        { vb = vmgb;  tok0 = (ch-2)*32; vstr = 1280; }
    bf16x8 v0 = *(const bf16x8*)(vb + (size_t)(h*32+col)*vstr + tok0 + quad*8);
    bf16x8 v1 = *(const bf16x8*)(vb + (size_t)(h*32+16+col)*vstr + tok0 + quad*8);
    if (ch + 1 < chEnd) {
      int c2 = ch + 1;
      const __bf16* kb2 = (c2 < 2) ? klocb + (size_t)(c2*32)*256
                                   : kmgb + (size_t)((c2-2)*32)*256;
      nk0 = *(const bf16x8*)(kb2 + (size_t)col*256 + h*32 + quad*8);
      nk1 = *(const bf16x8*)(kb2 + (size_t)(16+col)*256 + h*32 + quad*8);
    }
    f32x4 S0 = __builtin_amdgcn_mfma_f32_16x16x32_bf16(aq, k0, zero, 0, 0, 0);
    f32x4 S1 = __builtin_amdgcn_mfma_f32_16x16x32_bf16(aq, k1, zero, 0, 0, 0);
    __bf16* Pw = &Pb[wv][ch & 1][0][0];
    #pragma unroll
    for (int r = 0; r < 4; ++r) {
      float p0 = __expf(S0[r]);
      float p1 = __expf(S1[r]);
      ls[r] += p0 + p1;
      Pw[(quad*4+r)*40 + col]      = (__bf16)p0;
      Pw[(quad*4+r)*40 + 16 + col] = (__bf16)p1;
    }
    bf16x8 ap = *(const bf16x8*)(Pw + (size_t)col*40 + quad*8);
    O0 = __builtin_amdgcn_mfma_f32_16x16x32_bf16(ap, v0, O0, 0, 0, 0);
    O1 = __builtin_amdgcn_mfma_f32_16x16x32_bf16(ap, v1, O1, 0, 0, 0);
  }
  if (half == 1) {
    float* mg = &Mg[h][lane][0];
    #pragma unroll
    for (int r = 0; r < 4; ++r) { mg[r] = O0[r]; mg[4+r] = O1[r]; mg[8+r] = ls[r]; }
  }
  __syncthreads();
  if (half == 0) {
    const float* mg = &Mg[h][lane][0];
    #pragma unroll
    for (int r = 0; r < 4; ++r) { O0[r] += mg[r]; O1[r] += mg[4+r]; ls[r] += mg[8+r]; }
    #pragma unroll
    for (int r = 0; r < 4; ++r) {
      #pragma unroll
      for (int m = 1; m < 16; m <<= 1) ls[r] += __shfl_xor(ls[r], m);
    }
    __bf16* op = obf + ((size_t)(bw*16) + quad*4)*256 + h*32 + col;
    #pragma unroll
    for (int r = 0; r < 4; ++r) {
      float inv = 1.f / ls[r];
      op[(size_t)r*256]      = (__bf16)(O0[r]*inv);
      op[(size_t)r*256 + 16] = (__bf16)(O1[r]*inv);
    }
  }
}

// ---------------- out projection (MFMA) + residual + NCHW scatter ----------------
// wave = (window, n-half). D rows = 4 consecutive x pixels -> float4 stores.
__global__ __launch_bounds__(256) void gemm_out_mfma(
    const __bf16* __restrict__ obf, const __bf16* __restrict__ WoT,
    const float* __restrict__ outb, const float* __restrict__ Fres,
    float* __restrict__ Out)
{
  int tid = threadIdx.x, wv = tid >> 6, lane = tid & 63;
  int col = lane & 15, quad = lane >> 4;
  int win = blockIdx.x*2 + (wv >> 1);
  int nbase = (wv & 1)*8;
  int b = win >> 8, w = win & 255, wy = w >> 4, wx = w & 15;
  bf16x8 ao[8];
  const __bf16* op = obf + ((size_t)win*16 + col)*256 + quad*8;
  #pragma unroll
  for (int kk = 0; kk < 8; ++kk) ao[kk] = *(const bf16x8*)(op + kk*32);
  const f32x4 zero = {0.f,0.f,0.f,0.f};
  #pragma unroll
  for (int nt = 0; nt < 8; ++nt) {
    int n0 = (nbase+nt)*16;
    const __bf16* wp = WoT + ((size_t)(n0+col))*256 + quad*8;
    f32x4 acc = zero;
    #pragma unroll
    for (int kk = 0; kk < 8; ++kk) {
      bf16x8 wf = *(const bf16x8*)(wp + kk*32);
      acc = __builtin_amdgcn_mfma_f32_16x16x32_bf16(ao[kk], wf, acc, 0, 0, 0);
    }
    int ch = n0 + col;
    size_t off = ((size_t)(b*256 + ch))*HWSZ + (wy*4 + quad)*64 + wx*4;
    float4 r4 = *(const float4*)(Fres + off);
    float bn = outb[ch];
    float4 o;
    o.x = acc[0] + bn + r4.x; o.y = acc[1] + bn + r4.y;
    o.z = acc[2] + bn + r4.z; o.w = acc[3] + bn + r4.w;
    *(float4*)(Out + off) = o;
  }
}

extern "C" void kernel_launch(void* const* d_in, const int* in_sizes, int n_in,
                              void* d_out, int out_size, void* d_ws, size_t ws_size,
                              hipStream_t stream) {
  const float* F     = (const float*)d_in[0];
  const float* qkv_w = (const float*)d_in[1];
  const float* qkv_b = (const float*)d_in[2];
  const float* out_w = (const float*)d_in[3];
  const float* out_b = (const float*)d_in[4];
  const float* ln_w  = (const float*)d_in[5];
  const float* ln_b  = (const float*)d_in[6];
  float* out = (float*)d_out;

  __bf16* qnb   = (__bf16*)d_ws;             // 2,097,152 h
  __bf16* qbf   = qnb   + 2097152;           // 2,097,152 h
  __bf16* obf   = qbf   + 2097152;           // 2,097,152 h
  __bf16* kloc  = obf   + 2097152;           // 8,388,608 h
  __bf16* vloct = kloc  + 8388608;           // 8,388,608 h
  __bf16* kmg   = vloct + 8388608;           // 655,360 h
  __bf16* vmgt  = kmg   + 655360;            // 655,360 h
  __bf16* WT    = vmgt  + 655360;            // 196,608 h
  __bf16* WoT   = WT    + 196608;            // 65,536 h
  float*  mid   = (float*)(WoT + 65536);     // 524,288 f
  float*  glb   = mid   + 524288;            // 131,072 f
  // total ~52 MB

  transpose_w<<<dim3(12, 4), 256, 0, stream>>>(qkv_w, WT, 768);
  transpose_w<<<dim3(4, 4), 256, 0, stream>>>(out_w, WoT, 256);
  ln_qn_kernel<<<512, 256, 0, stream>>>(F, ln_w, ln_b, qnb);
  pool_mid_kernel<<<2048, 256, 0, stream>>>(F, mid);
  pool_glb_kernel<<<512, 256, 0, stream>>>(mid, glb);
  gemm_q_mfma<<<256, 256, 0, stream>>>(qnb, WT, qkv_b, qbf);
  loc_kv_mfma<<<512, 256, 0, stream>>>(F, WT, qkv_b, kloc, vloct);
  gemm_mg_kv<<<dim3(16, 8, 2), 256, 0, stream>>>(mid, 1024, 262144, qkv_w, qkv_b,
      kmg, (size_t)327680, vmgt, (size_t)327680, 1280);
  gemm_mg_kv<<<dim3(4, 8, 2), 256, 0, stream>>>(glb, 256, 65536, qkv_w, qkv_b,
      kmg + (size_t)1024*256, (size_t)327680, vmgt + 1024, (size_t)327680, 1280);
  attn_mfma<<<512, 1024, 0, stream>>>(qbf, kloc, vloct, kmg, vmgt, obf);
  gemm_out_mfma<<<256, 256, 0, stream>>>(obf, WoT, out_b, F, out);
}

// Round 5
// 292.987 us; speedup vs baseline: 1.0961x; 1.0961x over previous
//
#include <hip/hip_runtime.h>
#include <math.h>

#define HWSZ 4096   // 64*64
#define LDP 68      // padded LDS tile stride
#define QSCALE 0.17677669529663687f  // 1/sqrt(32)

typedef __bf16 bf16x2 __attribute__((ext_vector_type(2)));
typedef __bf16 bf16x4 __attribute__((ext_vector_type(4)));
typedef __bf16 bf16x8 __attribute__((ext_vector_type(8)));
typedef float  f32x4  __attribute__((ext_vector_type(4)));

// ---------------- scrambled-token LayerNorm -> qnb [8192][256] bf16 ----------------
__global__ __launch_bounds__(256) void ln_qn_kernel(
    const float* __restrict__ F, const float* __restrict__ lnw,
    const float* __restrict__ lnb, __bf16* __restrict__ qnb)
{
  __shared__ float sm[256][20];
  int bw = blockIdx.x;                 // b*256 + w
  int b = bw >> 8, w = bw & 255;
  int wy = w >> 4, wx = w & 15;
  int tid = threadIdx.x;               // = channel c
  const float* Fb = F + ((size_t)(b*256 + tid))*HWSZ + (wy*4)*64 + wx*4;
  #pragma unroll
  for (int py = 0; py < 4; ++py) {
    float4 v = *(const float4*)(Fb + py*64);
    sm[tid][py*4+0] = v.x; sm[tid][py*4+1] = v.y;
    sm[tid][py*4+2] = v.z; sm[tid][py*4+3] = v.w;
  }
  __syncthreads();
  int t = tid >> 4, th = tid & 15;
  float vals[16], s1 = 0.f, s2 = 0.f;
  #pragma unroll
  for (int p = 0; p < 16; ++p) {
    float x = sm[t*16 + th][p];
    vals[p] = x; s1 += x; s2 += x*x;
  }
  #pragma unroll
  for (int m = 1; m < 16; m <<= 1) { s1 += __shfl_xor(s1, m); s2 += __shfl_xor(s2, m); }
  float mean = s1 * (1.f/256.f);
  float var  = s2 * (1.f/256.f) - mean*mean;
  float rstd = rsqrtf(var + 1e-5f);
  __bf16* outp = qnb + ((size_t)(bw*16 + t))*256 + th*16;
  bf16x8 o0, o1;
  #pragma unroll
  for (int p = 0; p < 8; ++p) {
    o0[p] = (__bf16)((vals[p]-mean)*rstd*lnw[th*16+p] + lnb[th*16+p]);
    o1[p] = (__bf16)((vals[p+8]-mean)*rstd*lnw[th*16+p+8] + lnb[th*16+p+8]);
  }
  *(bf16x8*)outp = o0;
  *(bf16x8*)(outp+8) = o1;
}

// ---------------- fused pools: thread = 2x2 mid patch -> 1 glb elem ----------------
__global__ __launch_bounds__(256) void pool_kernel(
    const float* __restrict__ F, float* __restrict__ mid, float* __restrict__ glb)
{
  int bc = blockIdx.x;                  // b*256 + c
  int t = threadIdx.x;
  int gy = t >> 4, gx = t & 15;
  const float* p = F + (size_t)bc*HWSZ + (gy*4)*64 + gx*4;
  float4 r0 = *(const float4*)(p);
  float4 r1 = *(const float4*)(p + 64);
  float4 r2 = *(const float4*)(p + 128);
  float4 r3 = *(const float4*)(p + 192);
  float m00 = 0.25f*(r0.x + r0.y + r1.x + r1.y);
  float m01 = 0.25f*(r0.z + r0.w + r1.z + r1.w);
  float m10 = 0.25f*(r2.x + r2.y + r3.x + r3.y);
  float m11 = 0.25f*(r2.z + r2.w + r3.z + r3.w);
  float* mp = mid + (size_t)bc*1024 + (gy*2)*32 + gx*2;
  *(float2*)mp        = make_float2(m00, m01);
  *(float2*)(mp + 32) = make_float2(m10, m11);
  glb[(size_t)bc*256 + gy*16 + gx] = 0.25f*(m00 + m01 + m10 + m11);
}

// ---------------- one-time: both weight transposes in one dispatch ----------------
__global__ __launch_bounds__(256) void transpose_ws(
    const float* __restrict__ Wqkv, const float* __restrict__ Wout,
    __bf16* __restrict__ WT, __bf16* __restrict__ WoT)
{
  __shared__ float T[64][68];
  int bx = blockIdx.x;
  const float* W; __bf16* D; int ncols, n0;
  if (bx < 12) { W = Wqkv; D = WT;  ncols = 768; n0 = bx*64; }
  else         { W = Wout; D = WoT; ncols = 256; n0 = (bx-12)*64; }
  int k0 = blockIdx.y*64;
  int tid = threadIdx.x;
  int c4 = (tid & 15)*4, rr = tid >> 4;
  #pragma unroll
  for (int p = 0; p < 4; ++p) {
    int row = p*16 + rr;
    float4 v = *(const float4*)(W + (size_t)(k0+row)*ncols + n0 + c4);
    T[c4+0][row] = v.x; T[c4+1][row] = v.y; T[c4+2][row] = v.z; T[c4+3][row] = v.w;
  }
  __syncthreads();
  #pragma unroll
  for (int p = 0; p < 4; ++p) {
    int cc = p*16 + rr;
    bf16x4 o;
    o[0] = (__bf16)T[cc][c4+0]; o[1] = (__bf16)T[cc][c4+1];
    o[2] = (__bf16)T[cc][c4+2]; o[3] = (__bf16)T[cc][c4+3];
    *(bf16x4*)(D + (size_t)(n0+cc)*256 + k0 + c4) = o;
  }
}

// ---------------- q GEMM (MFMA, swapped operands) ----------------
__global__ __launch_bounds__(256) void gemm_q_mfma(
    const __bf16* __restrict__ qnb, const __bf16* __restrict__ WT,
    const float* __restrict__ qkvb, __bf16* __restrict__ qbf)
{
  int tid = threadIdx.x, wv = tid >> 6, lane = tid & 63;
  int col = lane & 15, quad = lane >> 4;
  int win = blockIdx.x*2 + (wv >> 1);
  int nbase = (wv & 1)*8;
  bf16x8 bq[8];
  const __bf16* qp = qnb + ((size_t)win*16 + col)*256 + quad*8;
  #pragma unroll
  for (int kk = 0; kk < 8; ++kk) bq[kk] = *(const bf16x8*)(qp + kk*32);
  const f32x4 zero = {0.f,0.f,0.f,0.f};
  #pragma unroll
  for (int nt = 0; nt < 8; ++nt) {
    int n0 = (nbase+nt)*16;
    const __bf16* wp = WT + ((size_t)(n0+col))*256 + quad*8;
    f32x4 acc = zero;
    #pragma unroll
    for (int kk = 0; kk < 8; ++kk) {
      bf16x8 wf = *(const bf16x8*)(wp + kk*32);
      acc = __builtin_amdgcn_mfma_f32_16x16x32_bf16(wf, bq[kk], acc, 0, 0, 0);
    }
    float4 b4 = *(const float4*)(qkvb + n0 + quad*4);
    float bb[4] = {b4.x,b4.y,b4.z,b4.w};
    bf16x4 o;
    #pragma unroll
    for (int r = 0; r < 4; ++r) o[r] = (__bf16)((acc[r]+bb[r])*QSCALE);
    *(bf16x4*)(qbf + ((size_t)win*16 + col)*256 + n0 + quad*4) = o;
  }
}

// ---------------- local KV: MFMA, one block per window, A gathered ONCE ----------------
__global__ __launch_bounds__(256) void loc_kv_mfma(
    const float* __restrict__ F, const __bf16* __restrict__ WT,
    const float* __restrict__ qkvb,
    __bf16* __restrict__ kloc, __bf16* __restrict__ vloct)
{
  __shared__ __bf16 As[64*264];
  int bw = blockIdx.x;
  int b = bw >> 8, w = bw & 255;
  int wy4 = ((w >> 4) << 2) - 2, wx4 = ((w & 15) << 2) - 2;
  int tid = threadIdx.x;
  {
    int xp = tid & 3;
    int dy = (tid >> 2) & 7;
    int cg = tid >> 5;
    int yy = wy4 + dy, xx = wx4 + xp*2;
    bool inb = ((unsigned)yy < 64u) && ((unsigned)xx < 64u);
    const float* Fp = F + ((size_t)b*256)*HWSZ + yy*64 + xx;
    #pragma unroll 4
    for (int i = 0; i < 32; ++i) {
      int ch = cg*32 + i;
      float2 v = make_float2(0.f, 0.f);
      if (inb) v = *(const float2*)(Fp + (size_t)ch*HWSZ);
      int t = ch >> 2, r = ch & 3;
      bf16x2 o; o[0] = (__bf16)v.x; o[1] = (__bf16)v.y;
      *(bf16x2*)&As[t*264 + r*64 + dy*8 + xp*2] = o;
    }
  }
  __syncthreads();
  int wv = tid >> 6, lane = tid & 63;
  int col = lane & 15, quad = lane >> 4;
  int m0 = wv*16;
  bf16x8 af[8];
  #pragma unroll
  for (int kk = 0; kk < 8; ++kk)
    af[kk] = *(const bf16x8*)&As[(m0+col)*264 + kk*32 + quad*8];

  const f32x4 zero = {0.f,0.f,0.f,0.f};
  #pragma unroll 2
  for (int nt = 0; nt < 32; ++nt) {
    int n = nt*16 + col;
    float bias_n = qkvb[256 + n];
    const __bf16* Wp = WT + (size_t)(256 + n)*256 + quad*8;
    f32x4 acc = zero;
    #pragma unroll
    for (int kk = 0; kk < 8; ++kk) {
      bf16x8 bv = *(const bf16x8*)(Wp + kk*32);
      acc = __builtin_amdgcn_mfma_f32_16x16x32_bf16(af[kk], bv, acc, 0, 0, 0);
    }
    if (nt < 16) {
      #pragma unroll
      for (int r = 0; r < 4; ++r)
        kloc[((size_t)bw*64 + m0 + quad*4 + r)*256 + n] = (__bf16)(acc[r] + bias_n);
    } else {
      bf16x4 o;
      #pragma unroll
      for (int r = 0; r < 4; ++r) o[r] = (__bf16)(acc[r] + bias_n);
      *(bf16x4*)(vloct + ((size_t)bw*256 + (n - 256))*64 + m0 + quad*4) = o;
    }
  }
}

// ---------------- mid/glb KV GEMM: A col-major [256][M], batched ----------------
__global__ __launch_bounds__(256) void gemm_mg_kv(
    const float* __restrict__ A, int Mstride, int Abatch,
    const float* __restrict__ Bw, const float* __restrict__ qkvb,
    __bf16* __restrict__ kdst, size_t kbatch,
    __bf16* __restrict__ vdst, size_t vbatch, int vstride)
{
  __shared__ float As[16][LDP];
  __shared__ float Bs[16][LDP];
  int bz = blockIdx.z;
  A += (size_t)bz*Abatch; kdst += (size_t)bz*kbatch; vdst += (size_t)bz*vbatch;
  int m0 = blockIdx.x*64;
  int nc = blockIdx.y;
  int bcol = 256 + nc*64;
  int tid = threadIdx.x, tx = tid & 15, ty = tid >> 4;
  float acc[4][4] = {};
  for (int k0 = 0; k0 < 256; k0 += 16) {
    {
      int kk = tid >> 4, mm = (tid & 15)*4;
      *(float4*)&As[kk][mm] = *(const float4*)(A + (size_t)(k0+kk)*Mstride + m0 + mm);
    }
    {
      int kk = tid >> 4, nn = (tid & 15)*4;
      *(float4*)&Bs[kk][nn] = *(const float4*)(Bw + (size_t)(k0+kk)*768 + bcol + nn);
    }
    __syncthreads();
    #pragma unroll
    for (int k = 0; k < 16; ++k) {
      float4 a = *(const float4*)&As[k][ty*4];
      float4 bv = *(const float4*)&Bs[k][tx*4];
      float av[4] = {a.x,a.y,a.z,a.w};
      float bb[4] = {bv.x,bv.y,bv.z,bv.w};
      #pragma unroll
      for (int i = 0; i < 4; ++i)
        #pragma unroll
        for (int j = 0; j < 4; ++j) acc[i][j] += av[i]*bb[j];
    }
    __syncthreads();
  }
  float4 b4 = *(const float4*)(qkvb + bcol + tx*4);
  float bb[4] = {b4.x,b4.y,b4.z,b4.w};
  if (nc < 4) {
    int n0 = nc*64;
    #pragma unroll
    for (int i = 0; i < 4; ++i) {
      bf16x4 o;
      #pragma unroll
      for (int j = 0; j < 4; ++j) o[j] = (__bf16)(acc[i][j]+bb[j]);
      *(bf16x4*)(kdst + (size_t)(m0+ty*4+i)*256 + n0 + tx*4) = o;
    }
  } else {
    int d0 = (nc-4)*64;
    #pragma unroll
    for (int j = 0; j < 4; ++j) {
      bf16x4 o;
      #pragma unroll
      for (int i = 0; i < 4; ++i) o[i] = (__bf16)(acc[i][j]+bb[j]);
      *(bf16x4*)(vdst + (size_t)(d0+tx*4+j)*vstride + m0 + ty*4) = o;
    }
  }
}

// ---------------- MFMA fused attention ----------------
// Block = (batch, head, group of 8 windows); wave = one window, all waves SAME head
// -> identical mid/glb K/V addresses across the 8 waves (L1-served, ~8x less L2 traffic).
// Deferred-PV pipeline: K/V prefetched one chunk ahead in registers; PV-MFMA of chunk
// ch-1 issues at iteration ch, with the P ds_read placed before the ds_writes of ch.
// Plain sum-exp (scores bounded: LN'd q x 0.02-scale weights) - no running max needed.
__global__ __launch_bounds__(512) void attn_mfma(
    const __bf16* __restrict__ qbf, const __bf16* __restrict__ kloc,
    const __bf16* __restrict__ vloct, const __bf16* __restrict__ kmg,
    const __bf16* __restrict__ vmgt, __bf16* __restrict__ obf)
{
  __shared__ __bf16 Pb[8][2][16][40];   // per-wave double buffer
  int blk = blockIdx.x;
  int b = blk >> 8, rr = blk & 255;
  int h = rr >> 5, wg = rr & 31;
  int tid = threadIdx.x, wv = tid >> 6, lane = tid & 63;
  int col = lane & 15, quad = lane >> 4;
  int bw = b*256 + wg*8 + wv;           // this wave's window

  bf16x8 aq = *(const bf16x8*)(qbf + ((size_t)(bw*16 + col))*256 + h*32 + quad*8);
  f32x4 O0 = {0.f,0.f,0.f,0.f}, O1 = {0.f,0.f,0.f,0.f};
  const f32x4 zero = {0.f,0.f,0.f,0.f};
  float ls[4] = {0.f,0.f,0.f,0.f};

  const __bf16* klocb = kloc  + (size_t)bw*16384 + h*32 + quad*8;
  const __bf16* vlocb = vloct + (size_t)bw*16384 + (size_t)(h*32)*64 + quad*8;
  const __bf16* kmgb  = kmg   + (size_t)b*327680 + h*32 + quad*8;
  const __bf16* vmgb  = vmgt  + (size_t)b*327680 + (size_t)(h*32)*1280 + quad*8;

  // prefetch chunk 0 (local)
  bf16x8 nk0 = *(const bf16x8*)(klocb + (size_t)col*256);
  bf16x8 nk1 = *(const bf16x8*)(klocb + (size_t)(16+col)*256);
  bf16x8 nv0 = *(const bf16x8*)(vlocb + (size_t)col*64);
  bf16x8 nv1 = *(const bf16x8*)(vlocb + (size_t)(16+col)*64);
  bf16x8 pv0, pv1;
  __bf16* PwBase = &Pb[wv][0][0][0];

  #pragma unroll 1
  for (int ch = 0; ch < 42; ++ch) {
    bf16x8 k0 = nk0, k1 = nk1, v0 = nv0, v1 = nv1;
    int nc = ch + 1;
    if (nc < 42) {
      if (nc < 2) {
        nk0 = *(const bf16x8*)(klocb + (size_t)(nc*32 + col)*256);
        nk1 = *(const bf16x8*)(klocb + (size_t)(nc*32 + 16 + col)*256);
        nv0 = *(const bf16x8*)(vlocb + (size_t)col*64 + nc*32);
        nv1 = *(const bf16x8*)(vlocb + (size_t)(16+col)*64 + nc*32);
      } else {
        int tok0 = (nc-2)*32;
        nk0 = *(const bf16x8*)(kmgb + (size_t)(tok0 + col)*256);
        nk1 = *(const bf16x8*)(kmgb + (size_t)(tok0 + 16 + col)*256);
        nv0 = *(const bf16x8*)(vmgb + (size_t)col*1280 + tok0);
        nv1 = *(const bf16x8*)(vmgb + (size_t)(16+col)*1280 + tok0);
      }
    }
    f32x4 S0 = __builtin_amdgcn_mfma_f32_16x16x32_bf16(aq, k0, zero, 0, 0, 0);
    f32x4 S1 = __builtin_amdgcn_mfma_f32_16x16x32_bf16(aq, k1, zero, 0, 0, 0);
    // read P(ch-1) BEFORE writing P(ch): breaks the same-iteration LDS round trip
    bf16x8 ap;
    if (ch > 0)
      ap = *(const bf16x8*)(PwBase + (size_t)((ch-1)&1)*640 + col*40 + quad*8);
    __bf16* Pw = PwBase + (size_t)(ch&1)*640;
    #pragma unroll
    for (int r = 0; r < 4; ++r) {
      float p0 = __expf(S0[r]);
      float p1 = __expf(S1[r]);
      ls[r] += p0 + p1;
      Pw[(quad*4+r)*40 + col]      = (__bf16)p0;
      Pw[(quad*4+r)*40 + 16 + col] = (__bf16)p1;
    }
    if (ch > 0) {
      O0 = __builtin_amdgcn_mfma_f32_16x16x32_bf16(ap, pv0, O0, 0, 0, 0);
      O1 = __builtin_amdgcn_mfma_f32_16x16x32_bf16(ap, pv1, O1, 0, 0, 0);
    }
    pv0 = v0; pv1 = v1;
  }
  {
    bf16x8 ap = *(const bf16x8*)(PwBase + (size_t)(41&1)*640 + col*40 + quad*8);
    O0 = __builtin_amdgcn_mfma_f32_16x16x32_bf16(ap, pv0, O0, 0, 0, 0);
    O1 = __builtin_amdgcn_mfma_f32_16x16x32_bf16(ap, pv1, O1, 0, 0, 0);
  }
  #pragma unroll
  for (int r = 0; r < 4; ++r) {
    #pragma unroll
    for (int m = 1; m < 16; m <<= 1) ls[r] += __shfl_xor(ls[r], m);
  }
  __bf16* op = obf + ((size_t)(bw*16) + quad*4)*256 + h*32 + col;
  #pragma unroll
  for (int r = 0; r < 4; ++r) {
    float inv = 1.f / ls[r];
    op[(size_t)r*256]      = (__bf16)(O0[r]*inv);
    op[(size_t)r*256 + 16] = (__bf16)(O1[r]*inv);
  }
}

// ---------------- out projection (MFMA) + residual + NCHW scatter ----------------
__global__ __launch_bounds__(256) void gemm_out_mfma(
    const __bf16* __restrict__ obf, const __bf16* __restrict__ WoT,
    const float* __restrict__ outb, const float* __restrict__ Fres,
    float* __restrict__ Out)
{
  int tid = threadIdx.x, wv = tid >> 6, lane = tid & 63;
  int col = lane & 15, quad = lane >> 4;
  int win = blockIdx.x*2 + (wv >> 1);
  int nbase = (wv & 1)*8;
  int b = win >> 8, w = win & 255, wy = w >> 4, wx = w & 15;
  bf16x8 ao[8];
  const __bf16* op = obf + ((size_t)win*16 + col)*256 + quad*8;
  #pragma unroll
  for (int kk = 0; kk < 8; ++kk) ao[kk] = *(const bf16x8*)(op + kk*32);
  const f32x4 zero = {0.f,0.f,0.f,0.f};
  #pragma unroll
  for (int nt = 0; nt < 8; ++nt) {
    int n0 = (nbase+nt)*16;
    const __bf16* wp = WoT + ((size_t)(n0+col))*256 + quad*8;
    f32x4 acc = zero;
    #pragma unroll
    for (int kk = 0; kk < 8; ++kk) {
      bf16x8 wf = *(const bf16x8*)(wp + kk*32);
      acc = __builtin_amdgcn_mfma_f32_16x16x32_bf16(ao[kk], wf, acc, 0, 0, 0);
    }
    int ch = n0 + col;
    size_t off = ((size_t)(b*256 + ch))*HWSZ + (wy*4 + quad)*64 + wx*4;
    float4 r4 = *(const float4*)(Fres + off);
    float bn = outb[ch];
    float4 o;
    o.x = acc[0] + bn + r4.x; o.y = acc[1] + bn + r4.y;
    o.z = acc[2] + bn + r4.z; o.w = acc[3] + bn + r4.w;
    *(float4*)(Out + off) = o;
  }
}

extern "C" void kernel_launch(void* const* d_in, const int* in_sizes, int n_in,
                              void* d_out, int out_size, void* d_ws, size_t ws_size,
                              hipStream_t stream) {
  const float* F     = (const float*)d_in[0];
  const float* qkv_w = (const float*)d_in[1];
  const float* qkv_b = (const float*)d_in[2];
  const float* out_w = (const float*)d_in[3];
  const float* out_b = (const float*)d_in[4];
  const float* ln_w  = (const float*)d_in[5];
  const float* ln_b  = (const float*)d_in[6];
  float* out = (float*)d_out;

  __bf16* qnb   = (__bf16*)d_ws;             // 2,097,152 h
  __bf16* qbf   = qnb   + 2097152;           // 2,097,152 h
  __bf16* obf   = qbf   + 2097152;           // 2,097,152 h
  __bf16* kloc  = obf   + 2097152;           // 8,388,608 h
  __bf16* vloct = kloc  + 8388608;           // 8,388,608 h
  __bf16* kmg   = vloct + 8388608;           // 655,360 h
  __bf16* vmgt  = kmg   + 655360;            // 655,360 h
  __bf16* WT    = vmgt  + 655360;            // 196,608 h
  __bf16* WoT   = WT    + 196608;            // 65,536 h
  float*  mid   = (float*)(WoT + 65536);     // 524,288 f
  float*  glb   = mid   + 524288;            // 131,072 f

  transpose_ws<<<dim3(16, 4), 256, 0, stream>>>(qkv_w, out_w, WT, WoT);
  ln_qn_kernel<<<512, 256, 0, stream>>>(F, ln_w, ln_b, qnb);
  pool_kernel<<<512, 256, 0, stream>>>(F, mid, glb);
  gemm_q_mfma<<<256, 256, 0, stream>>>(qnb, WT, qkv_b, qbf);
  loc_kv_mfma<<<512, 256, 0, stream>>>(F, WT, qkv_b, kloc, vloct);
  gemm_mg_kv<<<dim3(16, 8, 2), 256, 0, stream>>>(mid, 1024, 262144, qkv_w, qkv_b,
      kmg, (size_t)327680, vmgt, (size_t)327680, 1280);
  gemm_mg_kv<<<dim3(4, 8, 2), 256, 0, stream>>>(glb, 256, 65536, qkv_w, qkv_b,
      kmg + (size_t)1024*256, (size_t)327680, vmgt + 1024, (size_t)327680, 1280);
  attn_mfma<<<512, 512, 0, stream>>>(qbf, kloc, vloct, kmg, vmgt, obf);
  gemm_out_mfma<<<256, 256, 0, stream>>>(obf, WoT, out_b, F, out);
}

// Round 6
// 281.448 us; speedup vs baseline: 1.1410x; 1.0410x over previous
//
#include <hip/hip_runtime.h>
#include <math.h>

#define HWSZ 4096   // 64*64
#define QSCALE 0.17677669529663687f  // 1/sqrt(32)

typedef __bf16 bf16x2 __attribute__((ext_vector_type(2)));
typedef __bf16 bf16x4 __attribute__((ext_vector_type(4)));
typedef __bf16 bf16x8 __attribute__((ext_vector_type(8)));
typedef float  f32x4  __attribute__((ext_vector_type(4)));

// ---------------- scrambled-token LayerNorm, strip version ----------------
// block = (b, wy, t): channels [16t,16t+16), rows [wy*4,wy*4+4), all 64 x.
// F loads fully coalesced; LN per (window wx, token t) via 16-lane shuffle group.
__global__ __launch_bounds__(256) void ln_qn_kernel(
    const float* __restrict__ F, const float* __restrict__ lnw,
    const float* __restrict__ lnb, __bf16* __restrict__ qnb)
{
  __shared__ float sm[16*269];         // [c16] stride 269, [py] stride 67, [x]
  int blk = blockIdx.x;                // b*256 + wy*16 + t
  int b = blk >> 8, wy = (blk >> 4) & 15, t = blk & 15;
  int tid = threadIdx.x;
  const float* Fb = F + ((size_t)(b*256 + t*16))*HWSZ + (wy*4)*64;
  int py = tid >> 6, x = tid & 63;
  #pragma unroll
  for (int j = 0; j < 16; ++j)
    sm[j*269 + py*67 + x] = Fb[(size_t)j*HWSZ + py*64 + x];
  __syncthreads();
  int wx = tid >> 4, cl = tid & 15;    // window wx, channel-lane cl
  float vals[16], s1 = 0.f, s2 = 0.f;
  #pragma unroll
  for (int p = 0; p < 16; ++p) {
    float v = sm[cl*269 + (p >> 2)*67 + wx*4 + (p & 3)];
    vals[p] = v; s1 += v; s2 += v*v;
  }
  #pragma unroll
  for (int m = 1; m < 16; m <<= 1) { s1 += __shfl_xor(s1, m); s2 += __shfl_xor(s2, m); }
  float mean = s1 * (1.f/256.f);
  float var  = s2 * (1.f/256.f) - mean*mean;
  float rstd = rsqrtf(var + 1e-5f);
  // c' = cl*16 + p
  __bf16* outp = qnb + (((size_t)(b*256 + wy*16 + wx))*16 + t)*256 + cl*16;
  bf16x8 o0, o1;
  #pragma unroll
  for (int p = 0; p < 8; ++p) {
    o0[p] = (__bf16)((vals[p]  -mean)*rstd*lnw[cl*16+p]   + lnb[cl*16+p]);
    o1[p] = (__bf16)((vals[p+8]-mean)*rstd*lnw[cl*16+p+8] + lnb[cl*16+p+8]);
  }
  *(bf16x8*)outp = o0;
  *(bf16x8*)(outp+8) = o1;
}

// ---------------- fused pools: thread = 2x2 mid patch -> 1 glb elem ----------------
__global__ __launch_bounds__(256) void pool_kernel(
    const float* __restrict__ F, float* __restrict__ mid, float* __restrict__ glb)
{
  int bc = blockIdx.x;                  // b*256 + c
  int t = threadIdx.x;
  int gy = t >> 4, gx = t & 15;
  const float* p = F + (size_t)bc*HWSZ + (gy*4)*64 + gx*4;
  float4 r0 = *(const float4*)(p);
  float4 r1 = *(const float4*)(p + 64);
  float4 r2 = *(const float4*)(p + 128);
  float4 r3 = *(const float4*)(p + 192);
  float m00 = 0.25f*(r0.x + r0.y + r1.x + r1.y);
  float m01 = 0.25f*(r0.z + r0.w + r1.z + r1.w);
  float m10 = 0.25f*(r2.x + r2.y + r3.x + r3.y);
  float m11 = 0.25f*(r2.z + r2.w + r3.z + r3.w);
  float* mp = mid + (size_t)bc*1024 + (gy*2)*32 + gx*2;
  *(float2*)mp        = make_float2(m00, m01);
  *(float2*)(mp + 32) = make_float2(m10, m11);
  glb[(size_t)bc*256 + gy*16 + gx] = 0.25f*(m00 + m01 + m10 + m11);
}

// ---------------- one-time: both weight transposes in one dispatch ----------------
__global__ __launch_bounds__(256) void transpose_ws(
    const float* __restrict__ Wqkv, const float* __restrict__ Wout,
    __bf16* __restrict__ WT, __bf16* __restrict__ WoT)
{
  __shared__ float T[64][68];
  int bx = blockIdx.x;
  const float* W; __bf16* D; int ncols, n0;
  if (bx < 12) { W = Wqkv; D = WT;  ncols = 768; n0 = bx*64; }
  else         { W = Wout; D = WoT; ncols = 256; n0 = (bx-12)*64; }
  int k0 = blockIdx.y*64;
  int tid = threadIdx.x;
  int c4 = (tid & 15)*4, rr = tid >> 4;
  #pragma unroll
  for (int p = 0; p < 4; ++p) {
    int row = p*16 + rr;
    float4 v = *(const float4*)(W + (size_t)(k0+row)*ncols + n0 + c4);
    T[c4+0][row] = v.x; T[c4+1][row] = v.y; T[c4+2][row] = v.z; T[c4+3][row] = v.w;
  }
  __syncthreads();
  #pragma unroll
  for (int p = 0; p < 4; ++p) {
    int cc = p*16 + rr;
    bf16x4 o;
    o[0] = (__bf16)T[cc][c4+0]; o[1] = (__bf16)T[cc][c4+1];
    o[2] = (__bf16)T[cc][c4+2]; o[3] = (__bf16)T[cc][c4+3];
    *(bf16x4*)(D + (size_t)(n0+cc)*256 + k0 + c4) = o;
  }
}

// ---------------- pooled tokens: transpose [c][tok] fp32 -> [tok][c] bf16 ----------------
// mgt[b][tok][c], tok 0..1023 = mid, 1024..1279 = glb
__global__ __launch_bounds__(256) void transpose_tok(
    const float* __restrict__ mid, const float* __restrict__ glb,
    __bf16* __restrict__ mgt)
{
  __shared__ float T[64][68];
  int t0 = blockIdx.x*64, c0 = blockIdx.y*64, b = blockIdx.z;
  const float* src; int stride, toff;
  if (t0 < 1024) { src = mid + ((size_t)(b*256 + c0))*1024; stride = 1024; toff = t0; }
  else           { src = glb + ((size_t)(b*256 + c0))*256;  stride = 256;  toff = t0 - 1024; }
  int tid = threadIdx.x;
  int c4 = (tid & 15)*4, rr = tid >> 4;
  #pragma unroll
  for (int p = 0; p < 4; ++p) {
    int row = p*16 + rr;                 // channel offset
    float4 v = *(const float4*)(src + (size_t)row*stride + toff + c4);
    T[c4+0][row] = v.x; T[c4+1][row] = v.y; T[c4+2][row] = v.z; T[c4+3][row] = v.w;
  }
  __syncthreads();
  #pragma unroll
  for (int p = 0; p < 4; ++p) {
    int tt = p*16 + rr;                  // token offset
    bf16x4 o;
    o[0] = (__bf16)T[tt][c4+0]; o[1] = (__bf16)T[tt][c4+1];
    o[2] = (__bf16)T[tt][c4+2]; o[3] = (__bf16)T[tt][c4+3];
    *(bf16x4*)(mgt + ((size_t)b*1280 + t0 + tt)*256 + c0 + c4) = o;
  }
}

// ---------------- q GEMM (MFMA, swapped operands) ----------------
__global__ __launch_bounds__(256) void gemm_q_mfma(
    const __bf16* __restrict__ qnb, const __bf16* __restrict__ WT,
    const float* __restrict__ qkvb, __bf16* __restrict__ qbf)
{
  int tid = threadIdx.x, wv = tid >> 6, lane = tid & 63;
  int col = lane & 15, quad = lane >> 4;
  int win = blockIdx.x*2 + (wv >> 1);
  int nbase = (wv & 1)*8;
  bf16x8 bq[8];
  const __bf16* qp = qnb + ((size_t)win*16 + col)*256 + quad*8;
  #pragma unroll
  for (int kk = 0; kk < 8; ++kk) bq[kk] = *(const bf16x8*)(qp + kk*32);
  const f32x4 zero = {0.f,0.f,0.f,0.f};
  #pragma unroll
  for (int nt = 0; nt < 8; ++nt) {
    int n0 = (nbase+nt)*16;
    const __bf16* wp = WT + ((size_t)(n0+col))*256 + quad*8;
    f32x4 acc = zero;
    #pragma unroll
    for (int kk = 0; kk < 8; ++kk) {
      bf16x8 wf = *(const bf16x8*)(wp + kk*32);
      acc = __builtin_amdgcn_mfma_f32_16x16x32_bf16(wf, bq[kk], acc, 0, 0, 0);
    }
    float4 b4 = *(const float4*)(qkvb + n0 + quad*4);
    float bb[4] = {b4.x,b4.y,b4.z,b4.w};
    bf16x4 o;
    #pragma unroll
    for (int r = 0; r < 4; ++r) o[r] = (__bf16)((acc[r]+bb[r])*QSCALE);
    *(bf16x4*)(qbf + ((size_t)win*16 + col)*256 + n0 + quad*4) = o;
  }
}

// ---------------- local KV: MFMA, one block per window, A gathered ONCE ----------------
__global__ __launch_bounds__(256) void loc_kv_mfma(
    const float* __restrict__ F, const __bf16* __restrict__ WT,
    const float* __restrict__ qkvb,
    __bf16* __restrict__ kloc, __bf16* __restrict__ vloct)
{
  __shared__ __bf16 As[64*264];
  int bw = blockIdx.x;
  int b = bw >> 8, w = bw & 255;
  int wy4 = ((w >> 4) << 2) - 2, wx4 = ((w & 15) << 2) - 2;
  int tid = threadIdx.x;
  {
    int xp = tid & 3;
    int dy = (tid >> 2) & 7;
    int cg = tid >> 5;
    int yy = wy4 + dy, xx = wx4 + xp*2;
    bool inb = ((unsigned)yy < 64u) && ((unsigned)xx < 64u);
    const float* Fp = F + ((size_t)b*256)*HWSZ + yy*64 + xx;
    #pragma unroll 4
    for (int i = 0; i < 32; ++i) {
      int ch = cg*32 + i;
      float2 v = make_float2(0.f, 0.f);
      if (inb) v = *(const float2*)(Fp + (size_t)ch*HWSZ);
      int t = ch >> 2, r = ch & 3;
      bf16x2 o; o[0] = (__bf16)v.x; o[1] = (__bf16)v.y;
      *(bf16x2*)&As[t*264 + r*64 + dy*8 + xp*2] = o;
    }
  }
  __syncthreads();
  int wv = tid >> 6, lane = tid & 63;
  int col = lane & 15, quad = lane >> 4;
  int m0 = wv*16;
  bf16x8 af[8];
  #pragma unroll
  for (int kk = 0; kk < 8; ++kk)
    af[kk] = *(const bf16x8*)&As[(m0+col)*264 + kk*32 + quad*8];

  const f32x4 zero = {0.f,0.f,0.f,0.f};
  #pragma unroll 2
  for (int nt = 0; nt < 32; ++nt) {
    int n = nt*16 + col;
    float bias_n = qkvb[256 + n];
    const __bf16* Wp = WT + (size_t)(256 + n)*256 + quad*8;
    f32x4 acc = zero;
    #pragma unroll
    for (int kk = 0; kk < 8; ++kk) {
      bf16x8 bv = *(const bf16x8*)(Wp + kk*32);
      acc = __builtin_amdgcn_mfma_f32_16x16x32_bf16(af[kk], bv, acc, 0, 0, 0);
    }
    if (nt < 16) {
      #pragma unroll
      for (int r = 0; r < 4; ++r)
        kloc[((size_t)bw*64 + m0 + quad*4 + r)*256 + n] = (__bf16)(acc[r] + bias_n);
    } else {
      bf16x4 o;
      #pragma unroll
      for (int r = 0; r < 4; ++r) o[r] = (__bf16)(acc[r] + bias_n);
      *(bf16x4*)(vloct + ((size_t)bw*256 + (n - 256))*64 + m0 + quad*4) = o;
    }
  }
}

// ---------------- mid/glb KV: MFMA over token-major mgt ----------------
// grid (20 tok-blocks, 4 n-quarters, 2 b); wave = 16 tokens.
__global__ __launch_bounds__(256) void mg_kv_mfma(
    const __bf16* __restrict__ mgt, const __bf16* __restrict__ WT,
    const float* __restrict__ qkvb,
    __bf16* __restrict__ kmg, __bf16* __restrict__ vmgt)
{
  int tb = blockIdx.x, nq = blockIdx.y, b = blockIdx.z;
  int tid = threadIdx.x, wv = tid >> 6, lane = tid & 63;
  int col = lane & 15, quad = lane >> 4;
  int m0 = tb*64 + wv*16;
  const __bf16* Ab = mgt + ((size_t)b*1280 + m0 + col)*256 + quad*8;
  bf16x8 af[8];
  #pragma unroll
  for (int kk = 0; kk < 8; ++kk) af[kk] = *(const bf16x8*)(Ab + kk*32);
  const f32x4 zero = {0.f,0.f,0.f,0.f};
  #pragma unroll 2
  for (int nt = nq*8; nt < nq*8 + 8; ++nt) {
    int n = nt*16 + col;                  // 0..511
    float bias_n = qkvb[256 + n];
    const __bf16* Wp = WT + (size_t)(256 + n)*256 + quad*8;
    f32x4 acc = zero;
    #pragma unroll
    for (int kk = 0; kk < 8; ++kk) {
      bf16x8 bv = *(const bf16x8*)(Wp + kk*32);
      acc = __builtin_amdgcn_mfma_f32_16x16x32_bf16(af[kk], bv, acc, 0, 0, 0);
    }
    if (nt < 16) {
      #pragma unroll
      for (int r = 0; r < 4; ++r)
        kmg[((size_t)b*1280 + m0 + quad*4 + r)*256 + n] = (__bf16)(acc[r] + bias_n);
    } else {
      bf16x4 o;
      #pragma unroll
      for (int r = 0; r < 4; ++r) o[r] = (__bf16)(acc[r] + bias_n);
      *(bf16x4*)(vmgt + ((size_t)b*256 + (n - 256))*1280 + m0 + quad*4) = o;
    }
  }
}

// ---------------- MFMA fused attention (unchanged from round 5) ----------------
__global__ __launch_bounds__(512) void attn_mfma(
    const __bf16* __restrict__ qbf, const __bf16* __restrict__ kloc,
    const __bf16* __restrict__ vloct, const __bf16* __restrict__ kmg,
    const __bf16* __restrict__ vmgt, __bf16* __restrict__ obf)
{
  __shared__ __bf16 Pb[8][2][16][40];
  int blk = blockIdx.x;
  int b = blk >> 8, rr = blk & 255;
  int h = rr >> 5, wg = rr & 31;
  int tid = threadIdx.x, wv = tid >> 6, lane = tid & 63;
  int col = lane & 15, quad = lane >> 4;
  int bw = b*256 + wg*8 + wv;

  bf16x8 aq = *(const bf16x8*)(qbf + ((size_t)(bw*16 + col))*256 + h*32 + quad*8);
  f32x4 O0 = {0.f,0.f,0.f,0.f}, O1 = {0.f,0.f,0.f,0.f};
  const f32x4 zero = {0.f,0.f,0.f,0.f};
  float ls[4] = {0.f,0.f,0.f,0.f};

  const __bf16* klocb = kloc  + (size_t)bw*16384 + h*32 + quad*8;
  const __bf16* vlocb = vloct + (size_t)bw*16384 + (size_t)(h*32)*64 + quad*8;
  const __bf16* kmgb  = kmg   + (size_t)b*327680 + h*32 + quad*8;
  const __bf16* vmgb  = vmgt  + (size_t)b*327680 + (size_t)(h*32)*1280 + quad*8;

  bf16x8 nk0 = *(const bf16x8*)(klocb + (size_t)col*256);
  bf16x8 nk1 = *(const bf16x8*)(klocb + (size_t)(16+col)*256);
  bf16x8 nv0 = *(const bf16x8*)(vlocb + (size_t)col*64);
  bf16x8 nv1 = *(const bf16x8*)(vlocb + (size_t)(16+col)*64);
  bf16x8 pv0, pv1;
  __bf16* PwBase = &Pb[wv][0][0][0];

  #pragma unroll 1
  for (int ch = 0; ch < 42; ++ch) {
    bf16x8 k0 = nk0, k1 = nk1, v0 = nv0, v1 = nv1;
    int nc = ch + 1;
    if (nc < 42) {
      if (nc < 2) {
        nk0 = *(const bf16x8*)(klocb + (size_t)(nc*32 + col)*256);
        nk1 = *(const bf16x8*)(klocb + (size_t)(nc*32 + 16 + col)*256);
        nv0 = *(const bf16x8*)(vlocb + (size_t)col*64 + nc*32);
        nv1 = *(const bf16x8*)(vlocb + (size_t)(16+col)*64 + nc*32);
      } else {
        int tok0 = (nc-2)*32;
        nk0 = *(const bf16x8*)(kmgb + (size_t)(tok0 + col)*256);
        nk1 = *(const bf16x8*)(kmgb + (size_t)(tok0 + 16 + col)*256);
        nv0 = *(const bf16x8*)(vmgb + (size_t)col*1280 + tok0);
        nv1 = *(const bf16x8*)(vmgb + (size_t)(16+col)*1280 + tok0);
      }
    }
    f32x4 S0 = __builtin_amdgcn_mfma_f32_16x16x32_bf16(aq, k0, zero, 0, 0, 0);
    f32x4 S1 = __builtin_amdgcn_mfma_f32_16x16x32_bf16(aq, k1, zero, 0, 0, 0);
    bf16x8 ap;
    if (ch > 0)
      ap = *(const bf16x8*)(PwBase + (size_t)((ch-1)&1)*640 + col*40 + quad*8);
    __bf16* Pw = PwBase + (size_t)(ch&1)*640;
    #pragma unroll
    for (int r = 0; r < 4; ++r) {
      float p0 = __expf(S0[r]);
      float p1 = __expf(S1[r]);
      ls[r] += p0 + p1;
      Pw[(quad*4+r)*40 + col]      = (__bf16)p0;
      Pw[(quad*4+r)*40 + 16 + col] = (__bf16)p1;
    }
    if (ch > 0) {
      O0 = __builtin_amdgcn_mfma_f32_16x16x32_bf16(ap, pv0, O0, 0, 0, 0);
      O1 = __builtin_amdgcn_mfma_f32_16x16x32_bf16(ap, pv1, O1, 0, 0, 0);
    }
    pv0 = v0; pv1 = v1;
  }
  {
    bf16x8 ap = *(const bf16x8*)(PwBase + (size_t)(41&1)*640 + col*40 + quad*8);
    O0 = __builtin_amdgcn_mfma_f32_16x16x32_bf16(ap, pv0, O0, 0, 0, 0);
    O1 = __builtin_amdgcn_mfma_f32_16x16x32_bf16(ap, pv1, O1, 0, 0, 0);
  }
  #pragma unroll
  for (int r = 0; r < 4; ++r) {
    #pragma unroll
    for (int m = 1; m < 16; m <<= 1) ls[r] += __shfl_xor(ls[r], m);
  }
  __bf16* op = obf + ((size_t)(bw*16) + quad*4)*256 + h*32 + col;
  #pragma unroll
  for (int r = 0; r < 4; ++r) {
    float inv = 1.f / ls[r];
    op[(size_t)r*256]      = (__bf16)(O0[r]*inv);
    op[(size_t)r*256 + 16] = (__bf16)(O1[r]*inv);
  }
}

// ---------------- out projection, strip version ----------------
// block = (b, wy, 64-ch quarter); 4 waves x 4 windows each; D staged in LDS bf16,
// then coalesced 256-B residual-fused fp32 stores.
__global__ __launch_bounds__(256) void gemm_out_strip(
    const __bf16* __restrict__ obf, const __bf16* __restrict__ WoT,
    const float* __restrict__ outb, const float* __restrict__ Fres,
    float* __restrict__ Out)
{
  __shared__ __bf16 strip[64*264];     // [c64] stride 264, [py] stride 66, [x64]
  int blk = blockIdx.x;                // b*64 + wy*4 + cq
  int b = blk >> 6, wy = (blk >> 2) & 15, cq = blk & 3;
  int c0 = cq*64;
  int tid = threadIdx.x, wv = tid >> 6, lane = tid & 63;
  int col = lane & 15, quad = lane >> 4;
  const f32x4 zero = {0.f,0.f,0.f,0.f};

  #pragma unroll
  for (int i = 0; i < 4; ++i) {
    int wx = wv*4 + i;
    int win = b*256 + wy*16 + wx;
    bf16x8 ao[8];
    const __bf16* op = obf + ((size_t)win*16 + col)*256 + quad*8;
    #pragma unroll
    for (int kk = 0; kk < 8; ++kk) ao[kk] = *(const bf16x8*)(op + kk*32);
    #pragma unroll
    for (int nt = 0; nt < 4; ++nt) {
      int n = c0 + nt*16 + col;
      const __bf16* wp = WoT + ((size_t)n)*256 + quad*8;
      f32x4 acc = zero;
      #pragma unroll
      for (int kk = 0; kk < 8; ++kk) {
        bf16x8 wf = *(const bf16x8*)(wp + kk*32);
        acc = __builtin_amdgcn_mfma_f32_16x16x32_bf16(ao[kk], wf, acc, 0, 0, 0);
      }
      // D[m=token=quad*4+r][n]: token = py*4+px -> py=quad, px=r
      bf16x4 o;
      #pragma unroll
      for (int r = 0; r < 4; ++r) o[r] = (__bf16)acc[r];
      *(bf16x4*)&strip[(nt*16+col)*264 + quad*66 + wx*4] = o;
    }
  }
  __syncthreads();
  #pragma unroll
  for (int j = 0; j < 16; ++j) {
    int f4 = j*256 + tid;               // [c][y][xq]
    int xq = f4 & 15, y = (f4 >> 4) & 3, c = f4 >> 6;
    bf16x4 d = *(const bf16x4*)&strip[c*264 + y*66 + xq*4];
    size_t off = ((size_t)(b*256 + c0 + c))*HWSZ + (wy*4 + y)*64 + xq*4;
    float4 r4 = *(const float4*)(Fres + off);
    float bn = outb[c0 + c];
    float4 o;
    o.x = (float)d[0] + bn + r4.x; o.y = (float)d[1] + bn + r4.y;
    o.z = (float)d[2] + bn + r4.z; o.w = (float)d[3] + bn + r4.w;
    *(float4*)(Out + off) = o;
  }
}

extern "C" void kernel_launch(void* const* d_in, const int* in_sizes, int n_in,
                              void* d_out, int out_size, void* d_ws, size_t ws_size,
                              hipStream_t stream) {
  const float* F     = (const float*)d_in[0];
  const float* qkv_w = (const float*)d_in[1];
  const float* qkv_b = (const float*)d_in[2];
  const float* out_w = (const float*)d_in[3];
  const float* out_b = (const float*)d_in[4];
  const float* ln_w  = (const float*)d_in[5];
  const float* ln_b  = (const float*)d_in[6];
  float* out = (float*)d_out;

  __bf16* qnb   = (__bf16*)d_ws;             // 2,097,152 h
  __bf16* qbf   = qnb   + 2097152;           // 2,097,152 h
  __bf16* obf   = qbf   + 2097152;           // 2,097,152 h
  __bf16* kloc  = obf   + 2097152;           // 8,388,608 h
  __bf16* vloct = kloc  + 8388608;           // 8,388,608 h
  __bf16* kmg   = vloct + 8388608;           // 655,360 h
  __bf16* vmgt  = kmg   + 655360;            // 655,360 h
  __bf16* mgt   = vmgt  + 655360;            // 655,360 h
  __bf16* WT    = mgt   + 655360;            // 196,608 h
  __bf16* WoT   = WT    + 196608;            // 65,536 h
  float*  mid   = (float*)(WoT + 65536);     // 524,288 f
  float*  glb   = mid   + 524288;            // 131,072 f

  transpose_ws<<<dim3(16, 4), 256, 0, stream>>>(qkv_w, out_w, WT, WoT);
  ln_qn_kernel<<<512, 256, 0, stream>>>(F, ln_w, ln_b, qnb);
  pool_kernel<<<512, 256, 0, stream>>>(F, mid, glb);
  transpose_tok<<<dim3(20, 4, 2), 256, 0, stream>>>(mid, glb, mgt);
  gemm_q_mfma<<<256, 256, 0, stream>>>(qnb, WT, qkv_b, qbf);
  loc_kv_mfma<<<512, 256, 0, stream>>>(F, WT, qkv_b, kloc, vloct);
  mg_kv_mfma<<<dim3(20, 4, 2), 256, 0, stream>>>(mgt, WT, qkv_b, kmg, vmgt);
  attn_mfma<<<512, 512, 0, stream>>>(qbf, kloc, vloct, kmg, vmgt, obf);
  gemm_out_strip<<<128, 256, 0, stream>>>(obf, WoT, out_b, F, out);
}

// Round 7
// 235.608 us; speedup vs baseline: 1.3630x; 1.1946x over previous
//
#include <hip/hip_runtime.h>
#include <math.h>

#define HWSZ 4096   // 64*64
// 1/sqrt(32) * log2(e): scores come out pre-multiplied by log2(e), so softmax
// uses p = exp2(S) (single v_exp_f32) -- mathematically identical.
#define QSCALE_L2E 0.25501988932587245f

typedef __bf16 bf16x2 __attribute__((ext_vector_type(2)));
typedef __bf16 bf16x4 __attribute__((ext_vector_type(4)));
typedef __bf16 bf16x8 __attribute__((ext_vector_type(8)));
typedef float  f32x4  __attribute__((ext_vector_type(4)));

// ---------------- scrambled-token LayerNorm, strip version ----------------
__global__ __launch_bounds__(256) void ln_qn_kernel(
    const float* __restrict__ F, const float* __restrict__ lnw,
    const float* __restrict__ lnb, __bf16* __restrict__ qnb)
{
  __shared__ float sm[16*269];         // [c16] stride 269, [py] stride 67, [x]
  int blk = blockIdx.x;                // b*256 + wy*16 + t
  int b = blk >> 8, wy = (blk >> 4) & 15, t = blk & 15;
  int tid = threadIdx.x;
  const float* Fb = F + ((size_t)(b*256 + t*16))*HWSZ + (wy*4)*64;
  int py = tid >> 6, x = tid & 63;
  #pragma unroll
  for (int j = 0; j < 16; ++j)
    sm[j*269 + py*67 + x] = Fb[(size_t)j*HWSZ + py*64 + x];
  __syncthreads();
  int wx = tid >> 4, cl = tid & 15;    // window wx, channel-lane cl
  float vals[16], s1 = 0.f, s2 = 0.f;
  #pragma unroll
  for (int p = 0; p < 16; ++p) {
    float v = sm[cl*269 + (p >> 2)*67 + wx*4 + (p & 3)];
    vals[p] = v; s1 += v; s2 += v*v;
  }
  #pragma unroll
  for (int m = 1; m < 16; m <<= 1) { s1 += __shfl_xor(s1, m); s2 += __shfl_xor(s2, m); }
  float mean = s1 * (1.f/256.f);
  float var  = s2 * (1.f/256.f) - mean*mean;
  float rstd = rsqrtf(var + 1e-5f);
  __bf16* outp = qnb + (((size_t)(b*256 + wy*16 + wx))*16 + t)*256 + cl*16;
  bf16x8 o0, o1;
  #pragma unroll
  for (int p = 0; p < 8; ++p) {
    o0[p] = (__bf16)((vals[p]  -mean)*rstd*lnw[cl*16+p]   + lnb[cl*16+p]);
    o1[p] = (__bf16)((vals[p+8]-mean)*rstd*lnw[cl*16+p+8] + lnb[cl*16+p+8]);
  }
  *(bf16x8*)outp = o0;
  *(bf16x8*)(outp+8) = o1;
}

// ---------------- fused pools: thread = 2x2 mid patch -> 1 glb elem ----------------
__global__ __launch_bounds__(256) void pool_kernel(
    const float* __restrict__ F, float* __restrict__ mid, float* __restrict__ glb)
{
  int bc = blockIdx.x;                  // b*256 + c
  int t = threadIdx.x;
  int gy = t >> 4, gx = t & 15;
  const float* p = F + (size_t)bc*HWSZ + (gy*4)*64 + gx*4;
  float4 r0 = *(const float4*)(p);
  float4 r1 = *(const float4*)(p + 64);
  float4 r2 = *(const float4*)(p + 128);
  float4 r3 = *(const float4*)(p + 192);
  float m00 = 0.25f*(r0.x + r0.y + r1.x + r1.y);
  float m01 = 0.25f*(r0.z + r0.w + r1.z + r1.w);
  float m10 = 0.25f*(r2.x + r2.y + r3.x + r3.y);
  float m11 = 0.25f*(r2.z + r2.w + r3.z + r3.w);
  float* mp = mid + (size_t)bc*1024 + (gy*2)*32 + gx*2;
  *(float2*)mp        = make_float2(m00, m01);
  *(float2*)(mp + 32) = make_float2(m10, m11);
  glb[(size_t)bc*256 + gy*16 + gx] = 0.25f*(m00 + m01 + m10 + m11);
}

// ---------------- one-time: both weight transposes in one dispatch ----------------
__global__ __launch_bounds__(256) void transpose_ws(
    const float* __restrict__ Wqkv, const float* __restrict__ Wout,
    __bf16* __restrict__ WT, __bf16* __restrict__ WoT)
{
  __shared__ float T[64][68];
  int bx = blockIdx.x;
  const float* W; __bf16* D; int ncols, n0;
  if (bx < 12) { W = Wqkv; D = WT;  ncols = 768; n0 = bx*64; }
  else         { W = Wout; D = WoT; ncols = 256; n0 = (bx-12)*64; }
  int k0 = blockIdx.y*64;
  int tid = threadIdx.x;
  int c4 = (tid & 15)*4, rr = tid >> 4;
  #pragma unroll
  for (int p = 0; p < 4; ++p) {
    int row = p*16 + rr;
    float4 v = *(const float4*)(W + (size_t)(k0+row)*ncols + n0 + c4);
    T[c4+0][row] = v.x; T[c4+1][row] = v.y; T[c4+2][row] = v.z; T[c4+3][row] = v.w;
  }
  __syncthreads();
  #pragma unroll
  for (int p = 0; p < 4; ++p) {
    int cc = p*16 + rr;
    bf16x4 o;
    o[0] = (__bf16)T[cc][c4+0]; o[1] = (__bf16)T[cc][c4+1];
    o[2] = (__bf16)T[cc][c4+2]; o[3] = (__bf16)T[cc][c4+3];
    *(bf16x4*)(D + (size_t)(n0+cc)*256 + k0 + c4) = o;
  }
}

// ---------------- pooled tokens: transpose [c][tok] fp32 -> [tok][c] bf16 ----------------
__global__ __launch_bounds__(256) void transpose_tok(
    const float* __restrict__ mid, const float* __restrict__ glb,
    __bf16* __restrict__ mgt)
{
  __shared__ float T[64][68];
  int t0 = blockIdx.x*64, c0 = blockIdx.y*64, b = blockIdx.z;
  const float* src; int stride, toff;
  if (t0 < 1024) { src = mid + ((size_t)(b*256 + c0))*1024; stride = 1024; toff = t0; }
  else           { src = glb + ((size_t)(b*256 + c0))*256;  stride = 256;  toff = t0 - 1024; }
  int tid = threadIdx.x;
  int c4 = (tid & 15)*4, rr = tid >> 4;
  #pragma unroll
  for (int p = 0; p < 4; ++p) {
    int row = p*16 + rr;                 // channel offset
    float4 v = *(const float4*)(src + (size_t)row*stride + toff + c4);
    T[c4+0][row] = v.x; T[c4+1][row] = v.y; T[c4+2][row] = v.z; T[c4+3][row] = v.w;
  }
  __syncthreads();
  #pragma unroll
  for (int p = 0; p < 4; ++p) {
    int tt = p*16 + rr;                  // token offset
    bf16x4 o;
    o[0] = (__bf16)T[tt][c4+0]; o[1] = (__bf16)T[tt][c4+1];
    o[2] = (__bf16)T[tt][c4+2]; o[3] = (__bf16)T[tt][c4+3];
    *(bf16x4*)(mgt + ((size_t)b*1280 + t0 + tt)*256 + c0 + c4) = o;
  }
}

// ---------------- q GEMM (MFMA, swapped operands); scale includes log2(e) ----------------
__global__ __launch_bounds__(256) void gemm_q_mfma(
    const __bf16* __restrict__ qnb, const __bf16* __restrict__ WT,
    const float* __restrict__ qkvb, __bf16* __restrict__ qbf)
{
  int tid = threadIdx.x, wv = tid >> 6, lane = tid & 63;
  int col = lane & 15, quad = lane >> 4;
  int win = blockIdx.x*2 + (wv >> 1);
  int nbase = (wv & 1)*8;
  bf16x8 bq[8];
  const __bf16* qp = qnb + ((size_t)win*16 + col)*256 + quad*8;
  #pragma unroll
  for (int kk = 0; kk < 8; ++kk) bq[kk] = *(const bf16x8*)(qp + kk*32);
  const f32x4 zero = {0.f,0.f,0.f,0.f};
  #pragma unroll
  for (int nt = 0; nt < 8; ++nt) {
    int n0 = (nbase+nt)*16;
    const __bf16* wp = WT + ((size_t)(n0+col))*256 + quad*8;
    f32x4 acc = zero;
    #pragma unroll
    for (int kk = 0; kk < 8; ++kk) {
      bf16x8 wf = *(const bf16x8*)(wp + kk*32);
      acc = __builtin_amdgcn_mfma_f32_16x16x32_bf16(wf, bq[kk], acc, 0, 0, 0);
    }
    float4 b4 = *(const float4*)(qkvb + n0 + quad*4);
    float bb[4] = {b4.x,b4.y,b4.z,b4.w};
    bf16x4 o;
    #pragma unroll
    for (int r = 0; r < 4; ++r) o[r] = (__bf16)((acc[r]+bb[r])*QSCALE_L2E);
    *(bf16x4*)(qbf + ((size_t)win*16 + col)*256 + n0 + quad*4) = o;
  }
}

// ---------------- local KV: MFMA, one block per window, A gathered ONCE ----------------
__global__ __launch_bounds__(256) void loc_kv_mfma(
    const float* __restrict__ F, const __bf16* __restrict__ WT,
    const float* __restrict__ qkvb,
    __bf16* __restrict__ kloc, __bf16* __restrict__ vloct)
{
  __shared__ __bf16 As[64*264];
  int bw = blockIdx.x;
  int b = bw >> 8, w = bw & 255;
  int wy4 = ((w >> 4) << 2) - 2, wx4 = ((w & 15) << 2) - 2;
  int tid = threadIdx.x;
  {
    int xp = tid & 3;
    int dy = (tid >> 2) & 7;
    int cg = tid >> 5;
    int yy = wy4 + dy, xx = wx4 + xp*2;
    bool inb = ((unsigned)yy < 64u) && ((unsigned)xx < 64u);
    const float* Fp = F + ((size_t)b*256)*HWSZ + yy*64 + xx;
    #pragma unroll 4
    for (int i = 0; i < 32; ++i) {
      int ch = cg*32 + i;
      float2 v = make_float2(0.f, 0.f);
      if (inb) v = *(const float2*)(Fp + (size_t)ch*HWSZ);
      int t = ch >> 2, r = ch & 3;
      bf16x2 o; o[0] = (__bf16)v.x; o[1] = (__bf16)v.y;
      *(bf16x2*)&As[t*264 + r*64 + dy*8 + xp*2] = o;
    }
  }
  __syncthreads();
  int wv = tid >> 6, lane = tid & 63;
  int col = lane & 15, quad = lane >> 4;
  int m0 = wv*16;
  bf16x8 af[8];
  #pragma unroll
  for (int kk = 0; kk < 8; ++kk)
    af[kk] = *(const bf16x8*)&As[(m0+col)*264 + kk*32 + quad*8];

  const f32x4 zero = {0.f,0.f,0.f,0.f};
  #pragma unroll 2
  for (int nt = 0; nt < 32; ++nt) {
    int n = nt*16 + col;
    float bias_n = qkvb[256 + n];
    const __bf16* Wp = WT + (size_t)(256 + n)*256 + quad*8;
    f32x4 acc = zero;
    #pragma unroll
    for (int kk = 0; kk < 8; ++kk) {
      bf16x8 bv = *(const bf16x8*)(Wp + kk*32);
      acc = __builtin_amdgcn_mfma_f32_16x16x32_bf16(af[kk], bv, acc, 0, 0, 0);
    }
    if (nt < 16) {
      #pragma unroll
      for (int r = 0; r < 4; ++r)
        kloc[((size_t)bw*64 + m0 + quad*4 + r)*256 + n] = (__bf16)(acc[r] + bias_n);
    } else {
      bf16x4 o;
      #pragma unroll
      for (int r = 0; r < 4; ++r) o[r] = (__bf16)(acc[r] + bias_n);
      *(bf16x4*)(vloct + ((size_t)bw*256 + (n - 256))*64 + m0 + quad*4) = o;
    }
  }
}

// ---------------- mid/glb KV: MFMA over token-major mgt ----------------
__global__ __launch_bounds__(256) void mg_kv_mfma(
    const __bf16* __restrict__ mgt, const __bf16* __restrict__ WT,
    const float* __restrict__ qkvb,
    __bf16* __restrict__ kmg, __bf16* __restrict__ vmgt)
{
  int tb = blockIdx.x, nq = blockIdx.y, b = blockIdx.z;
  int tid = threadIdx.x, wv = tid >> 6, lane = tid & 63;
  int col = lane & 15, quad = lane >> 4;
  int m0 = tb*64 + wv*16;
  const __bf16* Ab = mgt + ((size_t)b*1280 + m0 + col)*256 + quad*8;
  bf16x8 af[8];
  #pragma unroll
  for (int kk = 0; kk < 8; ++kk) af[kk] = *(const bf16x8*)(Ab + kk*32);
  const f32x4 zero = {0.f,0.f,0.f,0.f};
  #pragma unroll 2
  for (int nt = nq*8; nt < nq*8 + 8; ++nt) {
    int n = nt*16 + col;                  // 0..511
    float bias_n = qkvb[256 + n];
    const __bf16* Wp = WT + (size_t)(256 + n)*256 + quad*8;
    f32x4 acc = zero;
    #pragma unroll
    for (int kk = 0; kk < 8; ++kk) {
      bf16x8 bv = *(const bf16x8*)(Wp + kk*32);
      acc = __builtin_amdgcn_mfma_f32_16x16x32_bf16(af[kk], bv, acc, 0, 0, 0);
    }
    if (nt < 16) {
      #pragma unroll
      for (int r = 0; r < 4; ++r)
        kmg[((size_t)b*1280 + m0 + quad*4 + r)*256 + n] = (__bf16)(acc[r] + bias_n);
    } else {
      bf16x4 o;
      #pragma unroll
      for (int r = 0; r < 4; ++r) o[r] = (__bf16)(acc[r] + bias_n);
      *(bf16x4*)(vmgt + ((size_t)b*256 + (n - 256))*1280 + m0 + quad*4) = o;
    }
  }
}

// ---------------- MFMA fused attention with cooperative LDS K/V staging ----------------
// Block = (b, head, 8 windows); 8 waves share the head's mid/glb K/V. Each chunk's
// K slice [32 tok][64B] and V^T slice [32 dim][64B] are staged into LDS by all 512
// threads with COALESCED 8B loads (replaces per-wave 16-line-split gathers -- the
// r3-r6 85us wall). Triple-buffered, one barrier per chunk. p = exp2(S) (scale
// absorbed log2(e) in gemm_q). Local chunks 0,1 stay per-wave global.
__global__ __launch_bounds__(512) void attn_mfma(
    const __bf16* __restrict__ qbf, const __bf16* __restrict__ kloc,
    const __bf16* __restrict__ vloct, const __bf16* __restrict__ kmg,
    const __bf16* __restrict__ vmgt, __bf16* __restrict__ obf)
{
  __shared__ __bf16 Ks[3][32][40];      // 80-B rows (16B-aligned frag reads)
  __shared__ __bf16 Vs[3][32][40];
  __shared__ __bf16 Pb[8][2][16][40];
  int blk = blockIdx.x;
  int b = blk >> 8, rr = blk & 255;
  int h = rr >> 5, wg = rr & 31;
  int tid = threadIdx.x, wv = tid >> 6, lane = tid & 63;
  int col = lane & 15, quad = lane >> 4;
  int bw = b*256 + wg*8 + wv;           // this wave's window

  // staging assignment: thread -> one 8B piece of one K-or-V row
  int r64 = tid >> 3, l8 = tid & 7;
  bool isK = r64 < 32;
  int srow = isK ? r64 : r64 - 32;
  const __bf16* gbase = isK
      ? kmg  + ((size_t)(b*1280 + srow))*256 + h*32 + l8*4
      : vmgt + ((size_t)(b*256 + h*32 + srow))*1280 + l8*4;
  size_t gstride = isK ? 256 : 1;       // elements per token
  __bf16* lbase = isK ? &Ks[0][srow][l8*4] : &Vs[0][srow][l8*4];

  bf16x8 aq = *(const bf16x8*)(qbf + ((size_t)(bw*16 + col))*256 + h*32 + quad*8);
  f32x4 O0 = {0.f,0.f,0.f,0.f}, O1 = {0.f,0.f,0.f,0.f};
  const f32x4 zero = {0.f,0.f,0.f,0.f};
  float ls[4] = {0.f,0.f,0.f,0.f};
  __bf16* PwBase = &Pb[wv][0][0][0];

  // issue stage load for chunk 2 (tok0 = 0) early
  bf16x4 sreg = *(const bf16x4*)gbase;

  // ---- local chunks 0,1: per-window global loads (only 2 of 42) ----
  const __bf16* klocb = kloc  + (size_t)bw*16384 + h*32 + quad*8;
  const __bf16* vlocb = vloct + (size_t)bw*16384 + (size_t)(h*32)*64 + quad*8;
  #pragma unroll
  for (int ch = 0; ch < 2; ++ch) {
    bf16x8 k0 = *(const bf16x8*)(klocb + (size_t)(ch*32 + col)*256);
    bf16x8 k1 = *(const bf16x8*)(klocb + (size_t)(ch*32 + 16 + col)*256);
    bf16x8 v0 = *(const bf16x8*)(vlocb + (size_t)col*64 + ch*32);
    bf16x8 v1 = *(const bf16x8*)(vlocb + (size_t)(16+col)*64 + ch*32);
    f32x4 S0 = __builtin_amdgcn_mfma_f32_16x16x32_bf16(aq, k0, zero, 0, 0, 0);
    f32x4 S1 = __builtin_amdgcn_mfma_f32_16x16x32_bf16(aq, k1, zero, 0, 0, 0);
    __bf16* Pw = PwBase + (ch & 1)*640;
    #pragma unroll
    for (int r = 0; r < 4; ++r) {
      float p0 = __builtin_amdgcn_exp2f(S0[r]);
      float p1 = __builtin_amdgcn_exp2f(S1[r]);
      ls[r] += p0 + p1;
      Pw[(quad*4+r)*40 + col]      = (__bf16)p0;
      Pw[(quad*4+r)*40 + 16 + col] = (__bf16)p1;
    }
    bf16x8 ap = *(const bf16x8*)(Pw + (size_t)col*40 + quad*8);
    O0 = __builtin_amdgcn_mfma_f32_16x16x32_bf16(ap, v0, O0, 0, 0, 0);
    O1 = __builtin_amdgcn_mfma_f32_16x16x32_bf16(ap, v1, O1, 0, 0, 0);
  }

  // write chunk-2 slice, issue chunk-3 loads
  *(bf16x4*)(lbase + 2*1280) = sreg;
  sreg = *(const bf16x4*)(gbase + (size_t)32*gstride);
  __syncthreads();

  int buf = 2;
  #pragma unroll 1
  for (int ch = 2; ch < 42; ++ch) {
    int nbuf = (buf == 2) ? 0 : buf + 1;
    if (ch + 1 < 42) {
      *(bf16x4*)(lbase + nbuf*1280) = sreg;             // stage chunk ch+1
      if (ch + 2 < 42)
        sreg = *(const bf16x4*)(gbase + (size_t)(ch*32)*gstride);  // tok0(ch+2)
    }
    const __bf16* Kb = &Ks[buf][0][0];
    const __bf16* Vb = &Vs[buf][0][0];
    bf16x8 k0 = *(const bf16x8*)(Kb + col*40 + quad*8);
    bf16x8 k1 = *(const bf16x8*)(Kb + (16+col)*40 + quad*8);
    bf16x8 v0 = *(const bf16x8*)(Vb + col*40 + quad*8);
    bf16x8 v1 = *(const bf16x8*)(Vb + (16+col)*40 + quad*8);
    f32x4 S0 = __builtin_amdgcn_mfma_f32_16x16x32_bf16(aq, k0, zero, 0, 0, 0);
    f32x4 S1 = __builtin_amdgcn_mfma_f32_16x16x32_bf16(aq, k1, zero, 0, 0, 0);
    __bf16* Pw = PwBase + (ch & 1)*640;
    #pragma unroll
    for (int r = 0; r < 4; ++r) {
      float p0 = __builtin_amdgcn_exp2f(S0[r]);
      float p1 = __builtin_amdgcn_exp2f(S1[r]);
      ls[r] += p0 + p1;
      Pw[(quad*4+r)*40 + col]      = (__bf16)p0;
      Pw[(quad*4+r)*40 + 16 + col] = (__bf16)p1;
    }
    bf16x8 ap = *(const bf16x8*)(Pw + (size_t)col*40 + quad*8);
    O0 = __builtin_amdgcn_mfma_f32_16x16x32_bf16(ap, v0, O0, 0, 0, 0);
    O1 = __builtin_amdgcn_mfma_f32_16x16x32_bf16(ap, v1, O1, 0, 0, 0);
    buf = nbuf;
    __syncthreads();
  }

  #pragma unroll
  for (int r = 0; r < 4; ++r) {
    #pragma unroll
    for (int m = 1; m < 16; m <<= 1) ls[r] += __shfl_xor(ls[r], m);
  }
  __bf16* op = obf + ((size_t)(bw*16) + quad*4)*256 + h*32 + col;
  #pragma unroll
  for (int r = 0; r < 4; ++r) {
    float inv = 1.f / ls[r];
    op[(size_t)r*256]      = (__bf16)(O0[r]*inv);
    op[(size_t)r*256 + 16] = (__bf16)(O1[r]*inv);
  }
}

// ---------------- out projection, strip version ----------------
__global__ __launch_bounds__(256) void gemm_out_strip(
    const __bf16* __restrict__ obf, const __bf16* __restrict__ WoT,
    const float* __restrict__ outb, const float* __restrict__ Fres,
    float* __restrict__ Out)
{
  __shared__ __bf16 strip[64*264];     // [c64] stride 264, [py] stride 66, [x64]
  int blk = blockIdx.x;                // b*64 + wy*4 + cq
  int b = blk >> 6, wy = (blk >> 2) & 15, cq = blk & 3;
  int c0 = cq*64;
  int tid = threadIdx.x, wv = tid >> 6, lane = tid & 63;
  int col = lane & 15, quad = lane >> 4;
  const f32x4 zero = {0.f,0.f,0.f,0.f};

  #pragma unroll
  for (int i = 0; i < 4; ++i) {
    int wx = wv*4 + i;
    int win = b*256 + wy*16 + wx;
    bf16x8 ao[8];
    const __bf16* op = obf + ((size_t)win*16 + col)*256 + quad*8;
    #pragma unroll
    for (int kk = 0; kk < 8; ++kk) ao[kk] = *(const bf16x8*)(op + kk*32);
    #pragma unroll
    for (int nt = 0; nt < 4; ++nt) {
      int n = c0 + nt*16 + col;
      const __bf16* wp = WoT + ((size_t)n)*256 + quad*8;
      f32x4 acc = zero;
      #pragma unroll
      for (int kk = 0; kk < 8; ++kk) {
        bf16x8 wf = *(const bf16x8*)(wp + kk*32);
        acc = __builtin_amdgcn_mfma_f32_16x16x32_bf16(ao[kk], wf, acc, 0, 0, 0);
      }
      bf16x4 o;
      #pragma unroll
      for (int r = 0; r < 4; ++r) o[r] = (__bf16)acc[r];
      *(bf16x4*)&strip[(nt*16+col)*264 + quad*66 + wx*4] = o;
    }
  }
  __syncthreads();
  #pragma unroll
  for (int j = 0; j < 16; ++j) {
    int f4 = j*256 + tid;               // [c][y][xq]
    int xq = f4 & 15, y = (f4 >> 4) & 3, c = f4 >> 6;
    bf16x4 d = *(const bf16x4*)&strip[c*264 + y*66 + xq*4];
    size_t off = ((size_t)(b*256 + c0 + c))*HWSZ + (wy*4 + y)*64 + xq*4;
    float4 r4 = *(const float4*)(Fres + off);
    float bn = outb[c0 + c];
    float4 o;
    o.x = (float)d[0] + bn + r4.x; o.y = (float)d[1] + bn + r4.y;
    o.z = (float)d[2] + bn + r4.z; o.w = (float)d[3] + bn + r4.w;
    *(float4*)(Out + off) = o;
  }
}

extern "C" void kernel_launch(void* const* d_in, const int* in_sizes, int n_in,
                              void* d_out, int out_size, void* d_ws, size_t ws_size,
                              hipStream_t stream) {
  const float* F     = (const float*)d_in[0];
  const float* qkv_w = (const float*)d_in[1];
  const float* qkv_b = (const float*)d_in[2];
  const float* out_w = (const float*)d_in[3];
  const float* out_b = (const float*)d_in[4];
  const float* ln_w  = (const float*)d_in[5];
  const float* ln_b  = (const float*)d_in[6];
  float* out = (float*)d_out;

  __bf16* qnb   = (__bf16*)d_ws;             // 2,097,152 h
  __bf16* qbf   = qnb   + 2097152;           // 2,097,152 h
  __bf16* obf   = qbf   + 2097152;           // 2,097,152 h
  __bf16* kloc  = obf   + 2097152;           // 8,388,608 h
  __bf16* vloct = kloc  + 8388608;           // 8,388,608 h
  __bf16* kmg   = vloct + 8388608;           // 655,360 h
  __bf16* vmgt  = kmg   + 655360;            // 655,360 h
  __bf16* mgt   = vmgt  + 655360;            // 655,360 h
  __bf16* WT    = mgt   + 655360;            // 196,608 h
  __bf16* WoT   = WT    + 196608;            // 65,536 h
  float*  mid   = (float*)(WoT + 65536);     // 524,288 f
  float*  glb   = mid   + 524288;            // 131,072 f

  transpose_ws<<<dim3(16, 4), 256, 0, stream>>>(qkv_w, out_w, WT, WoT);
  ln_qn_kernel<<<512, 256, 0, stream>>>(F, ln_w, ln_b, qnb);
  pool_kernel<<<512, 256, 0, stream>>>(F, mid, glb);
  transpose_tok<<<dim3(20, 4, 2), 256, 0, stream>>>(mid, glb, mgt);
  gemm_q_mfma<<<256, 256, 0, stream>>>(qnb, WT, qkv_b, qbf);
  loc_kv_mfma<<<512, 256, 0, stream>>>(F, WT, qkv_b, kloc, vloct);
  mg_kv_mfma<<<dim3(20, 4, 2), 256, 0, stream>>>(mgt, WT, qkv_b, kmg, vmgt);
  attn_mfma<<<512, 512, 0, stream>>>(qbf, kloc, vloct, kmg, vmgt, obf);
  gemm_out_strip<<<128, 256, 0, stream>>>(obf, WoT, out_b, F, out);
}

// Round 8
// 201.960 us; speedup vs baseline: 1.5901x; 1.1666x over previous
//
#include <hip/hip_runtime.h>
#include <math.h>

#define HWSZ 4096   // 64*64
// 1/sqrt(32) * log2(e): scores come out pre-multiplied by log2(e), so softmax
// uses p = exp2(S) (single v_exp_f32) -- mathematically identical.
#define QSCALE_L2E 0.25501988932587245f

typedef __bf16 bf16x2 __attribute__((ext_vector_type(2)));
typedef __bf16 bf16x4 __attribute__((ext_vector_type(4)));
typedef __bf16 bf16x8 __attribute__((ext_vector_type(8)));
typedef float  f32x4  __attribute__((ext_vector_type(4)));

// ---------------- scrambled-token LayerNorm, strip version ----------------
__global__ __launch_bounds__(256) void ln_qn_kernel(
    const float* __restrict__ F, const float* __restrict__ lnw,
    const float* __restrict__ lnb, __bf16* __restrict__ qnb)
{
  __shared__ float sm[16*269];         // [c16] stride 269, [py] stride 67, [x]
  int blk = blockIdx.x;                // b*256 + wy*16 + t
  int b = blk >> 8, wy = (blk >> 4) & 15, t = blk & 15;
  int tid = threadIdx.x;
  const float* Fb = F + ((size_t)(b*256 + t*16))*HWSZ + (wy*4)*64;
  int py = tid >> 6, x = tid & 63;
  #pragma unroll
  for (int j = 0; j < 16; ++j)
    sm[j*269 + py*67 + x] = Fb[(size_t)j*HWSZ + py*64 + x];
  __syncthreads();
  int wx = tid >> 4, cl = tid & 15;    // window wx, channel-lane cl
  float vals[16], s1 = 0.f, s2 = 0.f;
  #pragma unroll
  for (int p = 0; p < 16; ++p) {
    float v = sm[cl*269 + (p >> 2)*67 + wx*4 + (p & 3)];
    vals[p] = v; s1 += v; s2 += v*v;
  }
  #pragma unroll
  for (int m = 1; m < 16; m <<= 1) { s1 += __shfl_xor(s1, m); s2 += __shfl_xor(s2, m); }
  float mean = s1 * (1.f/256.f);
  float var  = s2 * (1.f/256.f) - mean*mean;
  float rstd = rsqrtf(var + 1e-5f);
  __bf16* outp = qnb + (((size_t)(b*256 + wy*16 + wx))*16 + t)*256 + cl*16;
  bf16x8 o0, o1;
  #pragma unroll
  for (int p = 0; p < 8; ++p) {
    o0[p] = (__bf16)((vals[p]  -mean)*rstd*lnw[cl*16+p]   + lnb[cl*16+p]);
    o1[p] = (__bf16)((vals[p+8]-mean)*rstd*lnw[cl*16+p+8] + lnb[cl*16+p+8]);
  }
  *(bf16x8*)outp = o0;
  *(bf16x8*)(outp+8) = o1;
}

// ---------------- fused pools: thread = 2x2 mid patch -> 1 glb elem ----------------
__global__ __launch_bounds__(256) void pool_kernel(
    const float* __restrict__ F, float* __restrict__ mid, float* __restrict__ glb)
{
  int bc = blockIdx.x;                  // b*256 + c
  int t = threadIdx.x;
  int gy = t >> 4, gx = t & 15;
  const float* p = F + (size_t)bc*HWSZ + (gy*4)*64 + gx*4;
  float4 r0 = *(const float4*)(p);
  float4 r1 = *(const float4*)(p + 64);
  float4 r2 = *(const float4*)(p + 128);
  float4 r3 = *(const float4*)(p + 192);
  float m00 = 0.25f*(r0.x + r0.y + r1.x + r1.y);
  float m01 = 0.25f*(r0.z + r0.w + r1.z + r1.w);
  float m10 = 0.25f*(r2.x + r2.y + r3.x + r3.y);
  float m11 = 0.25f*(r2.z + r2.w + r3.z + r3.w);
  float* mp = mid + (size_t)bc*1024 + (gy*2)*32 + gx*2;
  *(float2*)mp        = make_float2(m00, m01);
  *(float2*)(mp + 32) = make_float2(m10, m11);
  glb[(size_t)bc*256 + gy*16 + gx] = 0.25f*(m00 + m01 + m10 + m11);
}

// ---------------- one-time: both weight transposes in one dispatch ----------------
__global__ __launch_bounds__(256) void transpose_ws(
    const float* __restrict__ Wqkv, const float* __restrict__ Wout,
    __bf16* __restrict__ WT, __bf16* __restrict__ WoT)
{
  __shared__ float T[64][68];
  int bx = blockIdx.x;
  const float* W; __bf16* D; int ncols, n0;
  if (bx < 12) { W = Wqkv; D = WT;  ncols = 768; n0 = bx*64; }
  else         { W = Wout; D = WoT; ncols = 256; n0 = (bx-12)*64; }
  int k0 = blockIdx.y*64;
  int tid = threadIdx.x;
  int c4 = (tid & 15)*4, rr = tid >> 4;
  #pragma unroll
  for (int p = 0; p < 4; ++p) {
    int row = p*16 + rr;
    float4 v = *(const float4*)(W + (size_t)(k0+row)*ncols + n0 + c4);
    T[c4+0][row] = v.x; T[c4+1][row] = v.y; T[c4+2][row] = v.z; T[c4+3][row] = v.w;
  }
  __syncthreads();
  #pragma unroll
  for (int p = 0; p < 4; ++p) {
    int cc = p*16 + rr;
    bf16x4 o;
    o[0] = (__bf16)T[cc][c4+0]; o[1] = (__bf16)T[cc][c4+1];
    o[2] = (__bf16)T[cc][c4+2]; o[3] = (__bf16)T[cc][c4+3];
    *(bf16x4*)(D + (size_t)(n0+cc)*256 + k0 + c4) = o;
  }
}

// ---------------- pooled tokens: transpose [c][tok] fp32 -> [tok][c] bf16 ----------------
__global__ __launch_bounds__(256) void transpose_tok(
    const float* __restrict__ mid, const float* __restrict__ glb,
    __bf16* __restrict__ mgt)
{
  __shared__ float T[64][68];
  int t0 = blockIdx.x*64, c0 = blockIdx.y*64, b = blockIdx.z;
  const float* src; int stride, toff;
  if (t0 < 1024) { src = mid + ((size_t)(b*256 + c0))*1024; stride = 1024; toff = t0; }
  else           { src = glb + ((size_t)(b*256 + c0))*256;  stride = 256;  toff = t0 - 1024; }
  int tid = threadIdx.x;
  int c4 = (tid & 15)*4, rr = tid >> 4;
  #pragma unroll
  for (int p = 0; p < 4; ++p) {
    int row = p*16 + rr;                 // channel offset
    float4 v = *(const float4*)(src + (size_t)row*stride + toff + c4);
    T[c4+0][row] = v.x; T[c4+1][row] = v.y; T[c4+2][row] = v.z; T[c4+3][row] = v.w;
  }
  __syncthreads();
  #pragma unroll
  for (int p = 0; p < 4; ++p) {
    int tt = p*16 + rr;                  // token offset
    bf16x4 o;
    o[0] = (__bf16)T[tt][c4+0]; o[1] = (__bf16)T[tt][c4+1];
    o[2] = (__bf16)T[tt][c4+2]; o[3] = (__bf16)T[tt][c4+3];
    *(bf16x4*)(mgt + ((size_t)b*1280 + t0 + tt)*256 + c0 + c4) = o;
  }
}

// ---------------- q GEMM (MFMA, swapped operands); scale includes log2(e) ----------------
__global__ __launch_bounds__(256) void gemm_q_mfma(
    const __bf16* __restrict__ qnb, const __bf16* __restrict__ WT,
    const float* __restrict__ qkvb, __bf16* __restrict__ qbf)
{
  int tid = threadIdx.x, wv = tid >> 6, lane = tid & 63;
  int col = lane & 15, quad = lane >> 4;
  int win = blockIdx.x*2 + (wv >> 1);
  int nbase = (wv & 1)*8;
  bf16x8 bq[8];
  const __bf16* qp = qnb + ((size_t)win*16 + col)*256 + quad*8;
  #pragma unroll
  for (int kk = 0; kk < 8; ++kk) bq[kk] = *(const bf16x8*)(qp + kk*32);
  const f32x4 zero = {0.f,0.f,0.f,0.f};
  #pragma unroll
  for (int nt = 0; nt < 8; ++nt) {
    int n0 = (nbase+nt)*16;
    const __bf16* wp = WT + ((size_t)(n0+col))*256 + quad*8;
    f32x4 acc = zero;
    #pragma unroll
    for (int kk = 0; kk < 8; ++kk) {
      bf16x8 wf = *(const bf16x8*)(wp + kk*32);
      acc = __builtin_amdgcn_mfma_f32_16x16x32_bf16(wf, bq[kk], acc, 0, 0, 0);
    }
    float4 b4 = *(const float4*)(qkvb + n0 + quad*4);
    float bb[4] = {b4.x,b4.y,b4.z,b4.w};
    bf16x4 o;
    #pragma unroll
    for (int r = 0; r < 4; ++r) o[r] = (__bf16)((acc[r]+bb[r])*QSCALE_L2E);
    *(bf16x4*)(qbf + ((size_t)win*16 + col)*256 + n0 + quad*4) = o;
  }
}

// ---------------- local KV: MFMA, block = window, WT tiles LDS-staged ----------------
// A (im2col, permutation of F) gathered once into LDS; each 16-n x 256-k WT tile
// (8 KB) is IDENTICAL across the 4 waves -> cooperatively staged into LDS with
// coalesced 32 B/thread loads (kills the 16-line split loads that made r7's
// version latency-bound at 77 us), triple-buffered, prefetch distance 2.
__global__ __launch_bounds__(256) void loc_kv_mfma(
    const float* __restrict__ F, const __bf16* __restrict__ WT,
    const float* __restrict__ qkvb,
    __bf16* __restrict__ kloc, __bf16* __restrict__ vloct)
{
  __shared__ __bf16 As[64*264];        // 33 KB
  __shared__ __bf16 Bs[3][16*264];     // 24.75 KB, 264-elem rows (2-way max alias)
  int bw = blockIdx.x;
  int b = bw >> 8, w = bw & 255;
  int wy4 = ((w >> 4) << 2) - 2, wx4 = ((w & 15) << 2) - 2;
  int tid = threadIdx.x;

  // ---- im2col gather stage (unchanged) ----
  {
    int xp = tid & 3;
    int dy = (tid >> 2) & 7;
    int cg = tid >> 5;
    int yy = wy4 + dy, xx = wx4 + xp*2;
    bool inb = ((unsigned)yy < 64u) && ((unsigned)xx < 64u);
    const float* Fp = F + ((size_t)b*256)*HWSZ + yy*64 + xx;
    #pragma unroll 4
    for (int i = 0; i < 32; ++i) {
      int ch = cg*32 + i;
      float2 v = make_float2(0.f, 0.f);
      if (inb) v = *(const float2*)(Fp + (size_t)ch*HWSZ);
      int t = ch >> 2, r = ch & 3;
      bf16x2 o; o[0] = (__bf16)v.x; o[1] = (__bf16)v.y;
      *(bf16x2*)&As[t*264 + r*64 + dy*8 + xp*2] = o;
    }
  }

  // ---- WT tile staging assignment: thread -> 32 B of one of 16 rows ----
  int brow = tid >> 4, bseg = tid & 15;
  const __bf16* wsrc = WT + ((size_t)(256 + brow))*256 + bseg*16;
  __bf16* bdst = (__bf16*)&Bs[0][0] + brow*264 + bseg*16;

  // prologue: tile 0 -> Bs[0], prefetch tile 1 into regs
  {
    bf16x8 a0 = *(const bf16x8*)wsrc;
    bf16x8 a1 = *(const bf16x8*)(wsrc + 8);
    *(bf16x8*)bdst = a0;
    *(bf16x8*)(bdst + 8) = a1;
  }
  bf16x8 g0 = *(const bf16x8*)(wsrc + (size_t)1*4096);
  bf16x8 g1 = *(const bf16x8*)(wsrc + (size_t)1*4096 + 8);
  __syncthreads();   // As + Bs[0] ready

  int wv = tid >> 6, lane = tid & 63;
  int col = lane & 15, quad = lane >> 4;
  int m0 = wv*16;
  bf16x8 af[8];
  #pragma unroll
  for (int kk = 0; kk < 8; ++kk)
    af[kk] = *(const bf16x8*)&As[(m0+col)*264 + kk*32 + quad*8];

  const f32x4 zero = {0.f,0.f,0.f,0.f};
  float biasv[2];
  biasv[0] = qkvb[256 + col];          // updated per nt below via reload (cheap, L1)
  #pragma unroll 1
  for (int nt = 0; nt < 32; ++nt) {
    int buf = nt - (nt/3)*3;           // nt % 3
    // issue prefetch of tile nt+2
    bf16x8 n0r, n1r;
    if (nt < 30) {
      const __bf16* p = wsrc + (size_t)(nt+2)*4096;
      n0r = *(const bf16x8*)p; n1r = *(const bf16x8*)(p + 8);
    }
    // write tile nt+1 (loaded last iteration) into buffer (nt+1)%3
    if (nt < 31) {
      int nb = nt + 1; nb -= (nb/3)*3;
      __bf16* d = (__bf16*)&Bs[0][0] + (size_t)nb*(16*264) + brow*264 + bseg*16;
      *(bf16x8*)d = g0;
      *(bf16x8*)(d + 8) = g1;
    }
    g0 = n0r; g1 = n1r;

    int n = nt*16 + col;
    float bias_n = qkvb[256 + n];
    const __bf16* Bb = (const __bf16*)&Bs[0][0] + (size_t)buf*(16*264);
    f32x4 acc = zero;
    #pragma unroll
    for (int kk = 0; kk < 8; ++kk) {
      bf16x8 bv = *(const bf16x8*)(Bb + col*264 + kk*32 + quad*8);
      acc = __builtin_amdgcn_mfma_f32_16x16x32_bf16(af[kk], bv, acc, 0, 0, 0);
    }
    if (nt < 16) {
      #pragma unroll
      for (int r = 0; r < 4; ++r)
        kloc[((size_t)bw*64 + m0 + quad*4 + r)*256 + n] = (__bf16)(acc[r] + bias_n);
    } else {
      bf16x4 o;
      #pragma unroll
      for (int r = 0; r < 4; ++r) o[r] = (__bf16)(acc[r] + bias_n);
      *(bf16x4*)(vloct + ((size_t)bw*256 + (n - 256))*64 + m0 + quad*4) = o;
    }
    __syncthreads();
  }
}

// ---------------- mid/glb KV: MFMA over token-major mgt ----------------
__global__ __launch_bounds__(256) void mg_kv_mfma(
    const __bf16* __restrict__ mgt, const __bf16* __restrict__ WT,
    const float* __restrict__ qkvb,
    __bf16* __restrict__ kmg, __bf16* __restrict__ vmgt)
{
  int tb = blockIdx.x, nq = blockIdx.y, b = blockIdx.z;
  int tid = threadIdx.x, wv = tid >> 6, lane = tid & 63;
  int col = lane & 15, quad = lane >> 4;
  int m0 = tb*64 + wv*16;
  const __bf16* Ab = mgt + ((size_t)b*1280 + m0 + col)*256 + quad*8;
  bf16x8 af[8];
  #pragma unroll
  for (int kk = 0; kk < 8; ++kk) af[kk] = *(const bf16x8*)(Ab + kk*32);
  const f32x4 zero = {0.f,0.f,0.f,0.f};
  #pragma unroll 2
  for (int nt = nq*8; nt < nq*8 + 8; ++nt) {
    int n = nt*16 + col;                  // 0..511
    float bias_n = qkvb[256 + n];
    const __bf16* Wp = WT + (size_t)(256 + n)*256 + quad*8;
    f32x4 acc = zero;
    #pragma unroll
    for (int kk = 0; kk < 8; ++kk) {
      bf16x8 bv = *(const bf16x8*)(Wp + kk*32);
      acc = __builtin_amdgcn_mfma_f32_16x16x32_bf16(af[kk], bv, acc, 0, 0, 0);
    }
    if (nt < 16) {
      #pragma unroll
      for (int r = 0; r < 4; ++r)
        kmg[((size_t)b*1280 + m0 + quad*4 + r)*256 + n] = (__bf16)(acc[r] + bias_n);
    } else {
      bf16x4 o;
      #pragma unroll
      for (int r = 0; r < 4; ++r) o[r] = (__bf16)(acc[r] + bias_n);
      *(bf16x4*)(vmgt + ((size_t)b*256 + (n - 256))*1280 + m0 + quad*4) = o;
    }
  }
}

// ---------------- MFMA fused attention with cooperative LDS K/V staging ----------------
__global__ __launch_bounds__(512) void attn_mfma(
    const __bf16* __restrict__ qbf, const __bf16* __restrict__ kloc,
    const __bf16* __restrict__ vloct, const __bf16* __restrict__ kmg,
    const __bf16* __restrict__ vmgt, __bf16* __restrict__ obf)
{
  __shared__ __bf16 Ks[3][32][40];      // 80-B rows (16B-aligned frag reads)
  __shared__ __bf16 Vs[3][32][40];
  __shared__ __bf16 Pb[8][2][16][40];
  int blk = blockIdx.x;
  int b = blk >> 8, rr = blk & 255;
  int h = rr >> 5, wg = rr & 31;
  int tid = threadIdx.x, wv = tid >> 6, lane = tid & 63;
  int col = lane & 15, quad = lane >> 4;
  int bw = b*256 + wg*8 + wv;           // this wave's window

  // staging assignment: thread -> one 8B piece of one K-or-V row
  int r64 = tid >> 3, l8 = tid & 7;
  bool isK = r64 < 32;
  int srow = isK ? r64 : r64 - 32;
  const __bf16* gbase = isK
      ? kmg  + ((size_t)(b*1280 + srow))*256 + h*32 + l8*4
      : vmgt + ((size_t)(b*256 + h*32 + srow))*1280 + l8*4;
  size_t gstride = isK ? 256 : 1;       // elements per token
  __bf16* lbase = isK ? &Ks[0][srow][l8*4] : &Vs[0][srow][l8*4];

  bf16x8 aq = *(const bf16x8*)(qbf + ((size_t)(bw*16 + col))*256 + h*32 + quad*8);
  f32x4 O0 = {0.f,0.f,0.f,0.f}, O1 = {0.f,0.f,0.f,0.f};
  const f32x4 zero = {0.f,0.f,0.f,0.f};
  float ls[4] = {0.f,0.f,0.f,0.f};
  __bf16* PwBase = &Pb[wv][0][0][0];

  // issue stage load for chunk 2 (tok0 = 0) early
  bf16x4 sreg = *(const bf16x4*)gbase;

  // ---- local chunks 0,1: per-window global loads (only 2 of 42) ----
  const __bf16* klocb = kloc  + (size_t)bw*16384 + h*32 + quad*8;
  const __bf16* vlocb = vloct + (size_t)bw*16384 + (size_t)(h*32)*64 + quad*8;
  #pragma unroll
  for (int ch = 0; ch < 2; ++ch) {
    bf16x8 k0 = *(const bf16x8*)(klocb + (size_t)(ch*32 + col)*256);
    bf16x8 k1 = *(const bf16x8*)(klocb + (size_t)(ch*32 + 16 + col)*256);
    bf16x8 v0 = *(const bf16x8*)(vlocb + (size_t)col*64 + ch*32);
    bf16x8 v1 = *(const bf16x8*)(vlocb + (size_t)(16+col)*64 + ch*32);
    f32x4 S0 = __builtin_amdgcn_mfma_f32_16x16x32_bf16(aq, k0, zero, 0, 0, 0);
    f32x4 S1 = __builtin_amdgcn_mfma_f32_16x16x32_bf16(aq, k1, zero, 0, 0, 0);
    __bf16* Pw = PwBase + (ch & 1)*640;
    #pragma unroll
    for (int r = 0; r < 4; ++r) {
      float p0 = __builtin_amdgcn_exp2f(S0[r]);
      float p1 = __builtin_amdgcn_exp2f(S1[r]);
      ls[r] += p0 + p1;
      Pw[(quad*4+r)*40 + col]      = (__bf16)p0;
      Pw[(quad*4+r)*40 + 16 + col] = (__bf16)p1;
    }
    bf16x8 ap = *(const bf16x8*)(Pw + (size_t)col*40 + quad*8);
    O0 = __builtin_amdgcn_mfma_f32_16x16x32_bf16(ap, v0, O0, 0, 0, 0);
    O1 = __builtin_amdgcn_mfma_f32_16x16x32_bf16(ap, v1, O1, 0, 0, 0);
  }

  // write chunk-2 slice, issue chunk-3 loads
  *(bf16x4*)(lbase + 2*1280) = sreg;
  sreg = *(const bf16x4*)(gbase + (size_t)32*gstride);
  __syncthreads();

  int buf = 2;
  #pragma unroll 1
  for (int ch = 2; ch < 42; ++ch) {
    int nbuf = (buf == 2) ? 0 : buf + 1;
    if (ch + 1 < 42) {
      *(bf16x4*)(lbase + nbuf*1280) = sreg;             // stage chunk ch+1
      if (ch + 2 < 42)
        sreg = *(const bf16x4*)(gbase + (size_t)(ch*32)*gstride);  // tok0(ch+2)
    }
    const __bf16* Kb = &Ks[buf][0][0];
    const __bf16* Vb = &Vs[buf][0][0];
    bf16x8 k0 = *(const bf16x8*)(Kb + col*40 + quad*8);
    bf16x8 k1 = *(const bf16x8*)(Kb + (16+col)*40 + quad*8);
    bf16x8 v0 = *(const bf16x8*)(Vb + col*40 + quad*8);
    bf16x8 v1 = *(const bf16x8*)(Vb + (16+col)*40 + quad*8);
    f32x4 S0 = __builtin_amdgcn_mfma_f32_16x16x32_bf16(aq, k0, zero, 0, 0, 0);
    f32x4 S1 = __builtin_amdgcn_mfma_f32_16x16x32_bf16(aq, k1, zero, 0, 0, 0);
    __bf16* Pw = PwBase + (ch & 1)*640;
    #pragma unroll
    for (int r = 0; r < 4; ++r) {
      float p0 = __builtin_amdgcn_exp2f(S0[r]);
      float p1 = __builtin_amdgcn_exp2f(S1[r]);
      ls[r] += p0 + p1;
      Pw[(quad*4+r)*40 + col]      = (__bf16)p0;
      Pw[(quad*4+r)*40 + 16 + col] = (__bf16)p1;
    }
    bf16x8 ap = *(const bf16x8*)(Pw + (size_t)col*40 + quad*8);
    O0 = __builtin_amdgcn_mfma_f32_16x16x32_bf16(ap, v0, O0, 0, 0, 0);
    O1 = __builtin_amdgcn_mfma_f32_16x16x32_bf16(ap, v1, O1, 0, 0, 0);
    buf = nbuf;
    __syncthreads();
  }

  #pragma unroll
  for (int r = 0; r < 4; ++r) {
    #pragma unroll
    for (int m = 1; m < 16; m <<= 1) ls[r] += __shfl_xor(ls[r], m);
  }
  __bf16* op = obf + ((size_t)(bw*16) + quad*4)*256 + h*32 + col;
  #pragma unroll
  for (int r = 0; r < 4; ++r) {
    float inv = 1.f / ls[r];
    op[(size_t)r*256]      = (__bf16)(O0[r]*inv);
    op[(size_t)r*256 + 16] = (__bf16)(O1[r]*inv);
  }
}

// ---------------- out projection, strip version ----------------
__global__ __launch_bounds__(256) void gemm_out_strip(
    const __bf16* __restrict__ obf, const __bf16* __restrict__ WoT,
    const float* __restrict__ outb, const float* __restrict__ Fres,
    float* __restrict__ Out)
{
  __shared__ __bf16 strip[64*264];     // [c64] stride 264, [py] stride 66, [x64]
  int blk = blockIdx.x;                // b*64 + wy*4 + cq
  int b = blk >> 6, wy = (blk >> 2) & 15, cq = blk & 3;
  int c0 = cq*64;
  int tid = threadIdx.x, wv = tid >> 6, lane = tid & 63;
  int col = lane & 15, quad = lane >> 4;
  const f32x4 zero = {0.f,0.f,0.f,0.f};

  #pragma unroll
  for (int i = 0; i < 4; ++i) {
    int wx = wv*4 + i;
    int win = b*256 + wy*16 + wx;
    bf16x8 ao[8];
    const __bf16* op = obf + ((size_t)win*16 + col)*256 + quad*8;
    #pragma unroll
    for (int kk = 0; kk < 8; ++kk) ao[kk] = *(const bf16x8*)(op + kk*32);
    #pragma unroll
    for (int nt = 0; nt < 4; ++nt) {
      int n = c0 + nt*16 + col;
      const __bf16* wp = WoT + ((size_t)n)*256 + quad*8;
      f32x4 acc = zero;
      #pragma unroll
      for (int kk = 0; kk < 8; ++kk) {
        bf16x8 wf = *(const bf16x8*)(wp + kk*32);
        acc = __builtin_amdgcn_mfma_f32_16x16x32_bf16(ao[kk], wf, acc, 0, 0, 0);
      }
      bf16x4 o;
      #pragma unroll
      for (int r = 0; r < 4; ++r) o[r] = (__bf16)acc[r];
      *(bf16x4*)&strip[(nt*16+col)*264 + quad*66 + wx*4] = o;
    }
  }
  __syncthreads();
  #pragma unroll
  for (int j = 0; j < 16; ++j) {
    int f4 = j*256 + tid;               // [c][y][xq]
    int xq = f4 & 15, y = (f4 >> 4) & 3, c = f4 >> 6;
    bf16x4 d = *(const bf16x4*)&strip[c*264 + y*66 + xq*4];
    size_t off = ((size_t)(b*256 + c0 + c))*HWSZ + (wy*4 + y)*64 + xq*4;
    float4 r4 = *(const float4*)(Fres + off);
    float bn = outb[c0 + c];
    float4 o;
    o.x = (float)d[0] + bn + r4.x; o.y = (float)d[1] + bn + r4.y;
    o.z = (float)d[2] + bn + r4.z; o.w = (float)d[3] + bn + r4.w;
    *(float4*)(Out + off) = o;
  }
}

extern "C" void kernel_launch(void* const* d_in, const int* in_sizes, int n_in,
                              void* d_out, int out_size, void* d_ws, size_t ws_size,
                              hipStream_t stream) {
  const float* F     = (const float*)d_in[0];
  const float* qkv_w = (const float*)d_in[1];
  const float* qkv_b = (const float*)d_in[2];
  const float* out_w = (const float*)d_in[3];
  const float* out_b = (const float*)d_in[4];
  const float* ln_w  = (const float*)d_in[5];
  const float* ln_b  = (const float*)d_in[6];
  float* out = (float*)d_out;

  __bf16* qnb   = (__bf16*)d_ws;             // 2,097,152 h
  __bf16* qbf   = qnb   + 2097152;           // 2,097,152 h
  __bf16* obf   = qbf   + 2097152;           // 2,097,152 h
  __bf16* kloc  = obf   + 2097152;           // 8,388,608 h
  __bf16* vloct = kloc  + 8388608;           // 8,388,608 h
  __bf16* kmg   = vloct + 8388608;           // 655,360 h
  __bf16* vmgt  = kmg   + 655360;            // 655,360 h
  __bf16* mgt   = vmgt  + 655360;            // 655,360 h
  __bf16* WT    = mgt   + 655360;            // 196,608 h
  __bf16* WoT   = WT    + 196608;            // 65,536 h
  float*  mid   = (float*)(WoT + 65536);     // 524,288 f
  float*  glb   = mid   + 524288;            // 131,072 f

  transpose_ws<<<dim3(16, 4), 256, 0, stream>>>(qkv_w, out_w, WT, WoT);
  ln_qn_kernel<<<512, 256, 0, stream>>>(F, ln_w, ln_b, qnb);
  pool_kernel<<<512, 256, 0, stream>>>(F, mid, glb);
  transpose_tok<<<dim3(20, 4, 2), 256, 0, stream>>>(mid, glb, mgt);
  gemm_q_mfma<<<256, 256, 0, stream>>>(qnb, WT, qkv_b, qbf);
  loc_kv_mfma<<<512, 256, 0, stream>>>(F, WT, qkv_b, kloc, vloct);
  mg_kv_mfma<<<dim3(20, 4, 2), 256, 0, stream>>>(mgt, WT, qkv_b, kmg, vmgt);
  attn_mfma<<<512, 512, 0, stream>>>(qbf, kloc, vloct, kmg, vmgt, obf);
  gemm_out_strip<<<128, 256, 0, stream>>>(obf, WoT, out_b, F, out);
}